// Round 10
// baseline (788.202 us; speedup 1.0000x reference)
//
#include <hip/hip_runtime.h>
#include <hip/hip_bf16.h>
#include <math.h>

#define ND 100000
#define NS 50000
#define NE1 500000
#define NE2 250000
#define DIM 128
#define NH 4
#define HDI 32
#define GRID_M 512    // MFMA proj kernels: 2048 waves
#define GRID_G 1024   // gateall: 4096 waves
#define GRID_E1 2048  // edge1e: 8192 waves
#define GRID_E2 1024  // edge2e: 4096 waves
#define NT1 (NE1 / 16)  // 31250 sorted 16-edge chunks
#define NT2 (NE2 / 16)  // 15625

typedef __hip_bfloat16 bf16;
typedef unsigned short u16;
typedef unsigned int u32;
typedef short sx8 __attribute__((ext_vector_type(8)));   // 8 bf16 MFMA A/B frag
typedef float fx4 __attribute__((ext_vector_type(4)));   // MFMA C/D frag

__device__ __forceinline__ float ldf(const float* p, size_t i) { return p[i]; }
__device__ __forceinline__ float ldf(const bf16* p, size_t i) { return __bfloat162float(p[i]); }
__device__ __forceinline__ float b2f(bf16 v) { return __bfloat162float(v); }

__device__ __forceinline__ u16 f2bfu(float f) {
    __hip_bfloat16 h = __float2bfloat16(f);
    union { __hip_bfloat16 b; u16 u; } c; c.b = h; return c.u;
}
// unpack a bf16 pair (one dword, little-endian) to two floats
__device__ __forceinline__ float2 bfp(u32 u) {
    float2 r;
    r.x = __uint_as_float(u << 16);
    r.y = __uint_as_float(u & 0xffff0000u);
    return r;
}
__device__ __forceinline__ sx8 pack8(float4 v0, float4 v1) {
    sx8 r;
    r[0] = (short)f2bfu(v0.x); r[1] = (short)f2bfu(v0.y);
    r[2] = (short)f2bfu(v0.z); r[3] = (short)f2bfu(v0.w);
    r[4] = (short)f2bfu(v1.x); r[5] = (short)f2bfu(v1.y);
    r[6] = (short)f2bfu(v1.z); r[7] = (short)f2bfu(v1.w);
    return r;
}
// A-fragment load: 8 consecutive input elems -> bf16x8
__device__ __forceinline__ sx8 lda8(const bf16* p) { return *(const sx8*)p; }
__device__ __forceinline__ sx8 lda8(const float* p) {
    return pack8(*(const float4*)p, *(const float4*)(p + 4));
}
// 4 consecutive values as float4
__device__ __forceinline__ float4 ld4(const float* p) { return *(const float4*)p; }
__device__ __forceinline__ float4 ld4(const bf16* p) {
    float2 a = bfp(*(const u32*)p);
    float2 b = bfp(*(const u32*)(p + 2));
    return make_float4(a.x, a.y, b.x, b.y);
}

// ---------- fast transcendentals (native v_exp/v_rcp; ~1-2 ulp) ----------
__device__ __forceinline__ float gelu_fast(float x) {
    float u2 = x * fmaf(x * x, 0.0713550f, 1.5957691f);
    u2 = fminf(u2, 40.0f);
    float t = __expf(u2);
    return x * t * __builtin_amdgcn_rcpf(t + 1.0f);
}
__device__ __forceinline__ float sigmoid_fast(float x) {
    return __builtin_amdgcn_rcpf(1.0f + __expf(-x));
}
__device__ __forceinline__ float exp_fast(float x) { return __expf(x); }

// ---------- per-wave LDS slab helpers (16 rows x 128 dims f32, XOR-swizzled) ----------
__device__ __forceinline__ void slab_store(float* Gw, const fx4* acc, int er, int lg) {
#pragma unroll
    for (int f = 0; f < 8; ++f)
#pragma unroll
        for (int r = 0; r < 4; ++r) {
            int row = 4 * lg + r;
            int byo = row * 512 + (((16 * f + er) * 4) ^ ((row & 7) << 4));
            *(float*)((char*)Gw + byo) = acc[f][r];
        }
}
__device__ __forceinline__ void slab_flush_bf16(const float* Gw, int lane, bf16* Yrow) {
#pragma unroll
    for (int i = 0; i < 16; ++i) {
        float2 gv = *(const float2*)((const char*)Gw + i * 512 + ((lane * 8) ^ ((i & 7) << 4)));
        u32 pk = ((u32)f2bfu(gv.y) << 16) | (u32)f2bfu(gv.x);
        *(u32*)&Yrow[(size_t)i * DIM + 2 * lane] = pk;
    }
}
__device__ __forceinline__ void sty2(float* p, float2 v) { *(float2*)p = v; }
__device__ __forceinline__ void sty2(bf16* p, float2 v) {
    *(u32*)p = ((u32)f2bfu(v.y) << 16) | (u32)f2bfu(v.x);
}

// ---------- diagnostics ----------
__global__ void fill16_kernel(u16* p, u16 v, size_t n) {
    size_t i = (size_t)blockIdx.x * blockDim.x + threadIdx.x;
    if (i < n) p[i] = v;
}

__global__ __launch_bounds__(64) void detect_kernel(const u16* w, int* flag) {
    int lane = threadIdx.x;
    int mx = 0;
    for (int j = 0; j < 32; ++j) {
        int i = 2 * (lane + 64 * j);
        int e = (w[i] >> 7) & 0xFF;
        mx = mx > e ? mx : e;
    }
    for (int d = 32; d; d >>= 1) { int o = __shfl_xor(mx, d); mx = mx > o ? mx : o; }
    if (lane == 0) flag[0] = (mx >= 0x90) ? 1 : 0;
}

// ---------- counting sort by dst ----------
__global__ __launch_bounds__(256) void hist_kernel(const int* __restrict__ dst, int ne,
                                                   u32* __restrict__ cnt) {
    int stride = gridDim.x * blockDim.x;
    for (int i = blockIdx.x * blockDim.x + threadIdx.x; i < ne; i += stride)
        atomicAdd(&cnt[dst[i]], 1u);
}

__global__ __launch_bounds__(256) void scanA_kernel(const u32* __restrict__ cnt, int nb,
                                                    u32* __restrict__ chk) {
    __shared__ u32 ws[4];
    int b = blockIdx.x, t = threadIdx.x;
    int i0 = b * 1024 + t * 4;
    u32 s = 0;
#pragma unroll
    for (int j = 0; j < 4; ++j) { int i = i0 + j; if (i < nb) s += cnt[i]; }
#pragma unroll
    for (int d = 1; d < 64; d <<= 1) s += __shfl_xor(s, d);
    if ((t & 63) == 0) ws[t >> 6] = s;
    __syncthreads();
    if (t == 0) chk[b] = ws[0] + ws[1] + ws[2] + ws[3];
}

__global__ __launch_bounds__(256) void scanB_kernel(u32* __restrict__ chk, int nc) {
    __shared__ u32 sh[256];
    int t = threadIdx.x;
    u32 v = (t < nc) ? chk[t] : 0u;
    sh[t] = v;
    __syncthreads();
    for (int d = 1; d < 256; d <<= 1) {
        u32 x = (t >= d) ? sh[t - d] : 0u;
        __syncthreads();
        if (t >= d) sh[t] += x;
        __syncthreads();
    }
    if (t < nc) chk[t] = sh[t] - v;
}

__global__ __launch_bounds__(256) void scanC_kernel(const u32* __restrict__ cnt, int nb,
                                                    const u32* __restrict__ chk,
                                                    u32* __restrict__ offs) {
    __shared__ u32 wsum[4];
    int b = blockIdx.x, t = threadIdx.x, lane = t & 63, wv = t >> 6;
    int i0 = b * 1024 + t * 4;
    u32 c0 = (i0 + 0 < nb) ? cnt[i0 + 0] : 0u;
    u32 c1 = (i0 + 1 < nb) ? cnt[i0 + 1] : 0u;
    u32 c2 = (i0 + 2 < nb) ? cnt[i0 + 2] : 0u;
    u32 c3 = (i0 + 3 < nb) ? cnt[i0 + 3] : 0u;
    u32 tot = c0 + c1 + c2 + c3;
    u32 inc = tot;
#pragma unroll
    for (int d = 1; d < 64; d <<= 1) { u32 x = __shfl_up(inc, d); if (lane >= d) inc += x; }
    if (lane == 63) wsum[wv] = inc;
    __syncthreads();
    u32 base = chk[b] + (inc - tot);
    for (int k = 0; k < wv; ++k) base += wsum[k];
    if (i0 + 0 < nb) offs[i0 + 0] = base;
    if (i0 + 1 < nb) offs[i0 + 1] = base + c0;
    if (i0 + 2 < nb) offs[i0 + 2] = base + c0 + c1;
    if (i0 + 3 < nb) offs[i0 + 3] = base + c0 + c1 + c2;
}

__global__ __launch_bounds__(256) void scatter_kernel(const int* __restrict__ dst, int ne,
                                                      u32* __restrict__ offs,
                                                      u32* __restrict__ perm) {
    int stride = gridDim.x * blockDim.x;
    for (int i = blockIdx.x * blockDim.x + threadIdx.x; i < ne; i += stride) {
        u32 p = atomicAdd(&offs[dst[i]], 1u);
        perm[p] = (u32)i;
    }
}

// ---------- prep: bf16 transposed weight tables + gate-MLP constants ----------
template <typename T>
__device__ __forceinline__ void transp(const T* W, u16* Bt, int gtid, int gstride) {
    for (int i = gtid; i < DIM * DIM; i += gstride) {
        int n = i >> 7, k = i & 127;
        Bt[i] = f2bfu(ldf(W, (size_t)k * DIM + n));
    }
}

// B1t[n][k] (n=0..127, k=0..31): k<8 -> gb1[n] + emb[k]@gW1[:32,n] (onehot-cat path);
// 8<=k<12 -> gW1[32+(k-8)][n] (cont path); else 0. GEMM1 becomes one K=32 MFMA.
template <typename T>
__device__ __forceinline__ void prep_body(
    const T* emb, const T* gW1, const T* gb1, const T* gW2,
    const T* Ws1, const T* Wd1, const T* Ws2, const T* Wd2, const T* Wod, const T* Wos,
    u16* B1t, float* gb2f, const T* gb2,
    u16* Btg, u16* Bs1, u16* Bd1, u16* Bs2, u16* Bd2, u16* Bod, u16* Bos)
{
    int gtid = blockIdx.x * blockDim.x + threadIdx.x;
    int gstride = gridDim.x * blockDim.x;
    for (int i = gtid; i < DIM * 32; i += gstride) {
        int n = i >> 5, k = i & 31;
        float v = 0.0f;
        if (k < 8) {
            v = ldf(gb1, n);
            for (int q = 0; q < 32; ++q) v += ldf(emb, k * 32 + q) * ldf(gW1, (size_t)q * DIM + n);
        } else if (k < 12) {
            v = ldf(gW1, (size_t)(32 + (k - 8)) * DIM + n);
        }
        B1t[i] = f2bfu(v);
    }
    for (int i = gtid; i < DIM; i += gstride) gb2f[i] = ldf(gb2, i);
    transp(gW2, Btg, gtid, gstride);
    transp(Ws1, Bs1, gtid, gstride);
    transp(Wd1, Bd1, gtid, gstride);
    transp(Ws2, Bs2, gtid, gstride);
    transp(Wd2, Bd2, gtid, gstride);
    transp(Wod, Bod, gtid, gstride);
    transp(Wos, Bos, gtid, gstride);
}

__global__ __launch_bounds__(256) void prep_kernel(
    const int* __restrict__ flag,
    const void* emb, const void* gW1, const void* gb1, const void* gW2, const void* gb2,
    const void* Ws1, const void* Wd1, const void* Ws2, const void* Wd2,
    const void* Wod, const void* Wos,
    u16* __restrict__ B1t, float* __restrict__ gb2f,
    u16* __restrict__ Btg, u16* __restrict__ Bs1, u16* __restrict__ Bd1,
    u16* __restrict__ Bs2, u16* __restrict__ Bd2, u16* __restrict__ Bod,
    u16* __restrict__ Bos)
{
    if (flag[0])
        prep_body((const float*)emb, (const float*)gW1, (const float*)gb1, (const float*)gW2,
                  (const float*)Ws1, (const float*)Wd1, (const float*)Ws2, (const float*)Wd2,
                  (const float*)Wod, (const float*)Wos,
                  B1t, gb2f, (const float*)gb2, Btg, Bs1, Bd1, Bs2, Bd2, Bod, Bos);
    else
        prep_body((const bf16*)emb, (const bf16*)gW1, (const bf16*)gb1, (const bf16*)gW2,
                  (const bf16*)Ws1, (const bf16*)Wd1, (const bf16*)Ws2, (const bf16*)Wd2,
                  (const bf16*)Wod, (const bf16*)Wos,
                  B1t, gb2f, (const bf16*)gb2, Btg, Bs1, Bd1, Bs2, Bd2, Bod, Bos);
}

// ---------- MFMA node projections: wave per 16-node tile ----------
template <typename T>
__device__ __forceinline__ void proj2m_body(
    float* Gw, const T* X, const T* b1, const T* b2,
    const u16* Bt1, const u16* Bt2, bf16* Y1, bf16* Y2, int N)
{
    int tid = threadIdx.x, lane = tid & 63, er = lane & 15, lg = lane >> 4;
    float c1i[8], c2i[8];
#pragma unroll
    for (int f = 0; f < 8; ++f) {
        c1i[f] = ldf(b1, 16 * f + er);
        c2i[f] = ldf(b2, 16 * f + er);
    }
    const int NW = GRID_M * 4;
    int gwid = blockIdx.x * 4 + (tid >> 6);
    int tiles = N / 16;
    for (int t = gwid; t < tiles; t += NW) {
        const T* xr = X + (size_t)(t * 16 + er) * DIM;
        sx8 a[4];
#pragma unroll
        for (int ks = 0; ks < 4; ++ks) a[ks] = lda8(xr + ks * 32 + lg * 8);
        fx4 acc1[8], acc2[8];
#pragma unroll
        for (int f = 0; f < 8; ++f) {
            acc1[f][0] = c1i[f]; acc1[f][1] = c1i[f]; acc1[f][2] = c1i[f]; acc1[f][3] = c1i[f];
            acc2[f][0] = c2i[f]; acc2[f][1] = c2i[f]; acc2[f][2] = c2i[f]; acc2[f][3] = c2i[f];
        }
#pragma unroll
        for (int ks = 0; ks < 4; ++ks)
#pragma unroll
            for (int f = 0; f < 8; ++f) {
                sx8 bv1 = *(const sx8*)(Bt1 + (size_t)(16 * f + er) * DIM + ks * 32 + lg * 8);
                acc1[f] = __builtin_amdgcn_mfma_f32_16x16x32_bf16(a[ks], bv1, acc1[f], 0, 0, 0);
                sx8 bv2 = *(const sx8*)(Bt2 + (size_t)(16 * f + er) * DIM + ks * 32 + lg * 8);
                acc2[f] = __builtin_amdgcn_mfma_f32_16x16x32_bf16(a[ks], bv2, acc2[f], 0, 0, 0);
            }
        slab_store(Gw, acc1, er, lg);
        slab_flush_bf16(Gw, lane, Y1 + (size_t)t * 16 * DIM);
        slab_store(Gw, acc2, er, lg);
        slab_flush_bf16(Gw, lane, Y2 + (size_t)t * 16 * DIM);
    }
}

__global__ __launch_bounds__(256) void proj2m_kernel(
    const int* __restrict__ flag, const void* X, const void* b1, const void* b2,
    const u16* __restrict__ Bt1, const u16* __restrict__ Bt2,
    bf16* __restrict__ Y1, bf16* __restrict__ Y2, int N)
{
    __shared__ float Gt[4][16 * 128];
    float* Gw = Gt[threadIdx.x >> 6];
    if (flag[0]) proj2m_body(Gw, (const float*)X, (const float*)b1, (const float*)b2, Bt1, Bt2, Y1, Y2, N);
    else         proj2m_body(Gw, (const bf16*)X, (const bf16*)b1, (const bf16*)b2, Bt1, Bt2, Y1, Y2, N);
}

template <typename T>
__device__ __forceinline__ void proj1m_body(
    float* Gw, const T* X, const T* b, const u16* Bt, bf16* Y, int N)
{
    int tid = threadIdx.x, lane = tid & 63, er = lane & 15, lg = lane >> 4;
    float ci[8];
#pragma unroll
    for (int f = 0; f < 8; ++f) ci[f] = ldf(b, 16 * f + er);
    const int NW = GRID_M * 4;
    int gwid = blockIdx.x * 4 + (tid >> 6);
    int tiles = N / 16;
    for (int t = gwid; t < tiles; t += NW) {
        const T* xr = X + (size_t)(t * 16 + er) * DIM;
        sx8 a[4];
#pragma unroll
        for (int ks = 0; ks < 4; ++ks) a[ks] = lda8(xr + ks * 32 + lg * 8);
        fx4 acc[8];
#pragma unroll
        for (int f = 0; f < 8; ++f) {
            acc[f][0] = ci[f]; acc[f][1] = ci[f]; acc[f][2] = ci[f]; acc[f][3] = ci[f];
        }
#pragma unroll
        for (int ks = 0; ks < 4; ++ks)
#pragma unroll
            for (int f = 0; f < 8; ++f) {
                sx8 bv = *(const sx8*)(Bt + (size_t)(16 * f + er) * DIM + ks * 32 + lg * 8);
                acc[f] = __builtin_amdgcn_mfma_f32_16x16x32_bf16(a[ks], bv, acc[f], 0, 0, 0);
            }
        slab_store(Gw, acc, er, lg);
        slab_flush_bf16(Gw, lane, Y + (size_t)t * 16 * DIM);
    }
}

__global__ __launch_bounds__(256) void proj1m_kernel(
    const int* __restrict__ flag, const void* X, const void* b,
    const u16* __restrict__ Bt, bf16* __restrict__ Y, int N)
{
    __shared__ float Gt[4][16 * 128];
    float* Gw = Gt[threadIdx.x >> 6];
    if (flag[0]) proj1m_body(Gw, (const float*)X, (const float*)b, Bt, Y, N);
    else         proj1m_body(Gw, (const bf16*)X, (const bf16*)b, Bt, Y, N);
}

// out[n] = (A[n] / s[n,head]) @ W + b  — division folded into A-fragment load
template <typename T>
__device__ __forceinline__ void projoutm_body(
    float* Gw, const float* A, const float* s, const T* b,
    const u16* Bt, T* out, int N)
{
    int tid = threadIdx.x, lane = tid & 63, er = lane & 15, lg = lane >> 4;
    float ci[8];
#pragma unroll
    for (int f = 0; f < 8; ++f) ci[f] = ldf(b, 16 * f + er);
    const int NW = GRID_M * 4;
    int gwid = blockIdx.x * 4 + (tid >> 6);
    int tiles = N / 16;
    for (int t = gwid; t < tiles; t += NW) {
        const float* ar = A + (size_t)(t * 16 + er) * DIM;
        const float* sr = s + (size_t)(t * 16 + er) * NH;
        sx8 a[4];
#pragma unroll
        for (int ks = 0; ks < 4; ++ks) {
            float inv = 1.0f / (sr[ks] + 1e-16f);   // head == ks for this k-range
            float4 v0 = *(const float4*)(ar + ks * 32 + lg * 8);
            float4 v1 = *(const float4*)(ar + ks * 32 + lg * 8 + 4);
            v0.x *= inv; v0.y *= inv; v0.z *= inv; v0.w *= inv;
            v1.x *= inv; v1.y *= inv; v1.z *= inv; v1.w *= inv;
            a[ks] = pack8(v0, v1);
        }
        fx4 acc[8];
#pragma unroll
        for (int f = 0; f < 8; ++f) {
            acc[f][0] = ci[f]; acc[f][1] = ci[f]; acc[f][2] = ci[f]; acc[f][3] = ci[f];
        }
#pragma unroll
        for (int ks = 0; ks < 4; ++ks)
#pragma unroll
            for (int f = 0; f < 8; ++f) {
                sx8 bv = *(const sx8*)(Bt + (size_t)(16 * f + er) * DIM + ks * 32 + lg * 8);
                acc[f] = __builtin_amdgcn_mfma_f32_16x16x32_bf16(a[ks], bv, acc[f], 0, 0, 0);
            }
        slab_store(Gw, acc, er, lg);
#pragma unroll
        for (int i = 0; i < 16; ++i) {
            float2 gv = *(const float2*)((const char*)Gw + i * 512 + ((lane * 8) ^ ((i & 7) << 4)));
            sty2(out + (size_t)(t * 16 + i) * DIM + 2 * lane, gv);
        }
    }
}

__global__ __launch_bounds__(256) void projoutm_kernel(
    const int* __restrict__ flag, const float* __restrict__ A, const float* __restrict__ s,
    const void* b, const u16* __restrict__ Bt, void* out, size_t off, int N)
{
    __shared__ float Gt[4][16 * 128];
    float* Gw = Gt[threadIdx.x >> 6];
    if (flag[0]) projoutm_body(Gw, A, s, (const float*)b, Bt, (float*)out + off, N);
    else         projoutm_body(Gw, A, s, (const bf16*)b, Bt, (bf16*)out + off, N);
}

// ---------- gate MLP kernel v5: one-hot MFMA gate + pipelined index prefetch ----------
// R4: no min-waves clamp. R5: no big reg-hoists. R6: no strided LDS tables.
// R7: one-hot MFMA for GEMM1. R8: full fusion serializes — keep split.
// R9: prefetch next tile's perm->cat/econt chain. R10: gates chunked to 32MB so the
// {gates + Xs/Xd + aggr} working set (~145MB) stays L3-resident (was ~240MB ~ L3 size,
// thrashing: 125MB WRITE + ~155MB re-FETCH of gates per round trip).
template <typename T>
__device__ __forceinline__ void gateall_body(
    float* Gw, const int* cat, const T* econt,
    const float* gb2f, const u16* B1t, const u16* Btg,
    const u32* perm, u32* gates, int c0, int c1)
{
    int tid = threadIdx.x;
    int lane = tid & 63;
    int er = lane & 15, lg = lane >> 4;

    float cinit[8];
#pragma unroll
    for (int f = 0; f < 8; ++f) cinit[f] = gb2f[16 * f + er];

    const int NW = GRID_G * 4;
    int span = c1 - c0;
    int w = blockIdx.x * 4 + (tid >> 6);
    int tpw = (span + NW - 1) / NW;
    int t0 = c0 + w * tpw, t1 = t0 + tpw;
    if (t1 > c1) t1 = c1;

    const fx4 zf = {0.f, 0.f, 0.f, 0.f};

    // preload tile t0's index/feature chain
    int c = 0;
    float4 fv = make_float4(0.f, 0.f, 0.f, 0.f);
    if (t0 < t1) {
        int e = (int)perm[t0 * 16 + er];
        c = cat[e];
        fv = ld4(econt + (size_t)e * 4);
    }

    for (int t = t0; t < t1; ++t) {
        // ---- prefetch tile t+1's chain (completes under this tile's compute) ----
        int tn = t + 1;
        int e_n = (tn < t1) ? (int)perm[tn * 16 + er] : 0;
        int c_n = cat[e_n];
        float4 fv_n = ld4(econt + (size_t)e_n * 4);

        // ---- A1 fragment in registers: [onehot8(cat), f0..f3, 0...] ----
        sx8 a1;
#pragma unroll
        for (int j = 0; j < 8; ++j) a1[j] = 0;
        if (lg == 0) {
#pragma unroll
            for (int j = 0; j < 8; ++j) a1[j] = (c == j) ? (short)0x3F80 : (short)0;
        } else if (lg == 1) {
            a1[0] = (short)f2bfu(fv.x); a1[1] = (short)f2bfu(fv.y);
            a1[2] = (short)f2bfu(fv.z); a1[3] = (short)f2bfu(fv.w);
        }

        // ---- GEMM1 on MFMA (K=32) ----
        fx4 p1[8];
#pragma unroll
        for (int f = 0; f < 8; ++f) {
            sx8 b1 = *(const sx8*)(B1t + (size_t)(16 * f + er) * 32 + lg * 8);
            p1[f] = __builtin_amdgcn_mfma_f32_16x16x32_bf16(a1, b1, zf, 0, 0, 0);
        }

        // ---- gelu -> swizzled slab (row=edge 4lg+r, col=dim 16f+er) ----
#pragma unroll
        for (int f = 0; f < 8; ++f)
#pragma unroll
            for (int r = 0; r < 4; ++r) {
                int row = 4 * lg + r;
                float hg = gelu_fast(p1[f][r]);
                int byo = row * 512 + (((16 * f + er) * 4) ^ ((row & 7) << 4));
                *(float*)((char*)Gw + byo) = hg;
            }

        // ---- read back h as GEMM2 A-fragments (row=er, dims ks*32+lg*8..+7) ----
        sx8 a2[4];
#pragma unroll
        for (int ks = 0; ks < 4; ++ks) {
            int base = ks * 128 + lg * 32;
            float4 v0 = *(const float4*)((const char*)Gw + er * 512 + ((base)      ^ ((er & 7) << 4)));
            float4 v1 = *(const float4*)((const char*)Gw + er * 512 + ((base + 16) ^ ((er & 7) << 4)));
            a2[ks] = pack8(v0, v1);
        }

        // ---- GEMM2 on MFMA ----
        fx4 acc[8];
#pragma unroll
        for (int f = 0; f < 8; ++f) {
            acc[f][0] = cinit[f]; acc[f][1] = cinit[f];
            acc[f][2] = cinit[f]; acc[f][3] = cinit[f];
        }
#pragma unroll
        for (int ks = 0; ks < 4; ++ks) {
#pragma unroll
            for (int f = 0; f < 8; ++f) {
                sx8 b = *(const sx8*)(Btg + (size_t)(16 * f + er) * DIM + ks * 32 + lg * 8);
                acc[f] = __builtin_amdgcn_mfma_f32_16x16x32_bf16(a2[ks], b, acc[f], 0, 0, 0);
            }
        }

        // ---- sigmoid -> slab ----
#pragma unroll
        for (int f = 0; f < 8; ++f)
#pragma unroll
            for (int r = 0; r < 4; ++r) {
                int row = 4 * lg + r;
                float g = sigmoid_fast(acc[f][r]);
                int byo = row * 512 + (((16 * f + er) * 4) ^ ((row & 7) << 4));
                *(float*)((char*)Gw + byo) = g;
            }

        // ---- pack bf16 pairs; coalesced 256B per edge, sorted-order index ----
#pragma unroll
        for (int i = 0; i < 16; ++i) {
            float2 gv = *(const float2*)((const char*)Gw + i * 512 + ((lane * 8) ^ ((i & 7) << 4)));
            u32 pk = ((u32)f2bfu(gv.y) << 16) | (u32)f2bfu(gv.x);
            gates[((size_t)(t - c0) * 16 + i) * 64 + lane] = pk;
        }

        c = c_n; fv = fv_n;
    }
}

__global__ __launch_bounds__(256) void gateall_kernel(
    const int* __restrict__ flag, const int* __restrict__ cat, const void* econt,
    const float* __restrict__ gb2f, const u16* __restrict__ B1t,
    const u16* __restrict__ Btg,
    const u32* __restrict__ perm, u32* __restrict__ gates, int c0, int c1)
{
    __shared__ float Gt[4][16 * 128];   // 32 KB
    float* Gw = Gt[threadIdx.x >> 6];
    if (flag[0]) gateall_body(Gw, cat, (const float*)econt, gb2f, B1t, Btg, perm, gates, c0, c1);
    else         gateall_body(Gw, cat, (const bf16*)econt, gb2f, B1t, Btg, perm, gates, c0, c1);
}

// ---------- edge1 epilogue: batched prefetch + pipelined index chain ----------
template <typename T>
__device__ __forceinline__ void edge1e_body(
    const bf16* Xs, const bf16* Xd,
    const int* src, const int* dst,
    const T* attn, const u32* perm, const u32* gates, int c0, int c1,
    float* s_out, float* aggr)
{
    int tid = threadIdx.x;
    int lane = tid & 63;
    int d0 = 2 * lane, h = lane >> 4, k0 = d0 & 31;
    float av0 = ldf(attn, h * HDI + k0), av1 = ldf(attn, h * HDI + k0 + 1);
    const float rs = 0.17677669529663688110f;

    const int NW = GRID_E1 * 4;
    int span = c1 - c0;
    int w = blockIdx.x * 4 + (tid >> 6);
    int cpw = (span + NW - 1) / NW;
    int t0 = c0 + w * cpw, t1 = t0 + cpw;
    if (t1 > c1) t1 = c1;

    int cur_di = -1;
    float acc0 = 0.f, acc1 = 0.f, ssum = 0.f;

    // preload tile t0's index chain (perm -> src/dst, 2 round trips)
    u32 sv = 0, dv = 0;
    if (t0 < t1 && lane < 16) {
        u32 pe = perm[t0 * 16 + lane];
        sv = (u32)src[(int)pe];
        dv = (u32)dst[(int)pe];
    }

    for (int t = t0; t < t1; ++t) {
        // prefetch next tile's index chain; completes under this tile's gathers+epilogue
        u32 sv_n = 0, dv_n = 0;
        int tn = t + 1;
        if (tn < t1 && lane < 16) {
            u32 pe_n = perm[tn * 16 + lane];
            sv_n = (u32)src[(int)pe_n];
            dv_n = (u32)dst[(int)pe_n];
        }

        // batched prefetch: 48 independent gathers in flight
        u32 xsp[16], xdp[16], gp[16];
#pragma unroll
        for (int i = 0; i < 16; ++i) {
            int si = (int)__builtin_amdgcn_readlane(sv, i);
            int di = (int)__builtin_amdgcn_readlane(dv, i);
            xsp[i] = *(const u32*)&Xs[(size_t)si * DIM + d0];
            xdp[i] = *(const u32*)&Xd[(size_t)di * DIM + d0];
            gp[i]  = gates[((size_t)(t - c0) * 16 + i) * 64 + lane];
        }
        // register-only compute; 16 independent shuffle/exp chains pipeline
#pragma unroll
        for (int i = 0; i < 16; ++i) {
            int di = (int)__builtin_amdgcn_readlane(dv, i);
            float2 sxy = bfp(xsp[i]);
            float2 dxy = bfp(xdp[i]);
            float2 gxy = bfp(gp[i]);
            if (di != cur_di) {
                if (cur_di >= 0) {
                    float* ap = &aggr[(size_t)cur_di * DIM + d0];
                    atomicAdd(ap, acc0);
                    atomicAdd(ap + 1, acc1);
                    if ((lane & 15) == 0)
                        atomicAdd(&s_out[(size_t)cur_di * NH + h], ssum);
                }
                cur_di = di; acc0 = 0.f; acc1 = 0.f; ssum = 0.f;
            }
            float m0 = (sxy.x + dxy.x) * gxy.x;
            float m1 = (sxy.y + dxy.y) * gxy.y;
            float p = (sxy.x * dxy.x + sxy.y * dxy.y) * rs + m0 * av0 + m1 * av1;
            p += __shfl_xor(p, 8);
            p += __shfl_xor(p, 4);
            p += __shfl_xor(p, 2);
            p += __shfl_xor(p, 1);
            float ev = exp_fast(fminf(p, 80.0f));
            acc0 = fmaf(ev, m0, acc0);
            acc1 = fmaf(ev, m1, acc1);
            ssum += ev;
        }

        sv = sv_n; dv = dv_n;
    }
    if (cur_di >= 0) {
        float* ap = &aggr[(size_t)cur_di * DIM + d0];
        atomicAdd(ap, acc0);
        atomicAdd(ap + 1, acc1);
        if ((lane & 15) == 0)
            atomicAdd(&s_out[(size_t)cur_di * NH + h], ssum);
    }
}

__global__ __launch_bounds__(256) void edge1e_kernel(
    const int* __restrict__ flag,
    const bf16* __restrict__ Xs, const bf16* __restrict__ Xd,
    const int* __restrict__ src, const int* __restrict__ dst,
    const void* attn, const u32* __restrict__ perm, const u32* __restrict__ gates,
    int c0, int c1, float* __restrict__ s_out, float* __restrict__ aggr)
{
    if (flag[0]) edge1e_body(Xs, Xd, src, dst, (const float*)attn, perm, gates, c0, c1, s_out, aggr);
    else         edge1e_body(Xs, Xd, src, dst, (const bf16*)attn, perm, gates, c0, c1, s_out, aggr);
}

// ---------- edge2 epilogue: batched prefetch + pipelined index chain, no gate ----------
template <typename T>
__device__ __forceinline__ void edge2e_body(
    const bf16* Xs, const bf16* Xd,
    const int* src, const int* dst,
    const T* attn, const u32* perm, float* s_out, float* aggr)
{
    int tid = threadIdx.x;
    int lane = tid & 63;
    int d0 = 2 * lane, h = lane >> 4, k0 = d0 & 31;
    float av0 = ldf(attn, h * HDI + k0), av1 = ldf(attn, h * HDI + k0 + 1);
    const float rs = 0.17677669529663688110f;

    const int NW = GRID_E2 * 4;
    int w = blockIdx.x * 4 + (tid >> 6);
    int cpw = (NT2 + NW - 1) / NW;
    int t0 = w * cpw, t1 = t0 + cpw;
    if (t1 > NT2) t1 = NT2;

    int cur_di = -1;
    float acc0 = 0.f, acc1 = 0.f, ssum = 0.f;

    u32 sv = 0, dv = 0;
    if (t0 < t1 && lane < 16) {
        u32 pe = perm[t0 * 16 + lane];
        sv = (u32)src[(int)pe];
        dv = (u32)dst[(int)pe];
    }

    for (int t = t0; t < t1; ++t) {
        u32 sv_n = 0, dv_n = 0;
        int tn = t + 1;
        if (tn < t1 && lane < 16) {
            u32 pe_n = perm[tn * 16 + lane];
            sv_n = (u32)src[(int)pe_n];
            dv_n = (u32)dst[(int)pe_n];
        }

        u32 xsp[16], xdp[16];
#pragma unroll
        for (int i = 0; i < 16; ++i) {
            int si = (int)__builtin_amdgcn_readlane(sv, i);
            int di = (int)__builtin_amdgcn_readlane(dv, i);
            xsp[i] = *(const u32*)&Xs[(size_t)si * DIM + d0];
            xdp[i] = *(const u32*)&Xd[(size_t)di * DIM + d0];
        }
#pragma unroll
        for (int i = 0; i < 16; ++i) {
            int di = (int)__builtin_amdgcn_readlane(dv, i);
            float2 sxy = bfp(xsp[i]);
            float2 dxy = bfp(xdp[i]);
            if (di != cur_di) {
                if (cur_di >= 0) {
                    float* ap = &aggr[(size_t)cur_di * DIM + d0];
                    atomicAdd(ap, acc0);
                    atomicAdd(ap + 1, acc1);
                    if ((lane & 15) == 0)
                        atomicAdd(&s_out[(size_t)cur_di * NH + h], ssum);
                }
                cur_di = di; acc0 = 0.f; acc1 = 0.f; ssum = 0.f;
            }
            float m0 = sxy.x + dxy.x;
            float m1 = sxy.y + dxy.y;
            float p = (sxy.x * dxy.x + sxy.y * dxy.y) * rs + m0 * av0 + m1 * av1;
            p += __shfl_xor(p, 8);
            p += __shfl_xor(p, 4);
            p += __shfl_xor(p, 2);
            p += __shfl_xor(p, 1);
            float ev = exp_fast(fminf(p, 80.0f));
            acc0 = fmaf(ev, m0, acc0);
            acc1 = fmaf(ev, m1, acc1);
            ssum += ev;
        }

        sv = sv_n; dv = dv_n;
    }
    if (cur_di >= 0) {
        float* ap = &aggr[(size_t)cur_di * DIM + d0];
        atomicAdd(ap, acc0);
        atomicAdd(ap + 1, acc1);
        if ((lane & 15) == 0)
            atomicAdd(&s_out[(size_t)cur_di * NH + h], ssum);
    }
}

__global__ __launch_bounds__(256) void edge2e_kernel(
    const int* __restrict__ flag,
    const bf16* __restrict__ Xs, const bf16* __restrict__ Xd,
    const int* __restrict__ src, const int* __restrict__ dst,
    const void* attn, const u32* __restrict__ perm,
    float* __restrict__ s_out, float* __restrict__ aggr)
{
    if (flag[0]) edge2e_body(Xs, Xd, src, dst, (const float*)attn, perm, s_out, aggr);
    else         edge2e_body(Xs, Xd, src, dst, (const bf16*)attn, perm, s_out, aggr);
}

extern "C" void kernel_launch(void* const* d_in, const int* in_sizes, int n_in,
                              void* d_out, int out_size, void* d_ws, size_t ws_size,
                              hipStream_t stream)
{
    const void* x_drug  = d_in[0];
    const void* x_dis   = d_in[1];
    const void* e1_cont = d_in[2];
    const void* W_src1  = d_in[3];
    const void* b_src1  = d_in[4];
    const void* W_dst1  = d_in[5];
    const void* b_dst1  = d_in[6];
    const void* attn1   = d_in[7];
    const void* emb1    = d_in[8];
    const void* gW1     = d_in[9];
    const void* gb1     = d_in[10];
    const void* gW2     = d_in[11];
    const void* gb2     = d_in[12];
    const void* W_src2  = d_in[13];
    const void* b_src2  = d_in[14];
    const void* W_dst2  = d_in[15];
    const void* b_dst2  = d_in[16];
    const void* attn2   = d_in[17];
    const void* Wo_drug = d_in[18];
    const void* bo_drug = d_in[19];
    const void* Wo_dis  = d_in[20];
    const void* bo_dis  = d_in[21];
    const int* e1_src = (const int*)d_in[22];
    const int* e1_dst = (const int*)d_in[23];
    const int* e2_src = (const int*)d_in[24];
    const int* e2_dst = (const int*)d_in[25];
    const int* e1_cat = (const int*)d_in[26];

    bool sizes_ok = (n_in == 27)
        && in_sizes[0] == ND * DIM && in_sizes[1] == NS * DIM
        && in_sizes[2] == NE1 * 4
        && in_sizes[3] == DIM * DIM && in_sizes[4] == DIM
        && in_sizes[5] == DIM * DIM && in_sizes[6] == DIM
        && in_sizes[7] == NH * HDI && in_sizes[8] == 8 * 32
        && in_sizes[9] == 36 * DIM && in_sizes[10] == DIM
        && in_sizes[11] == DIM * DIM && in_sizes[12] == DIM
        && in_sizes[13] == DIM * DIM && in_sizes[17] == NH * HDI
        && in_sizes[18] == DIM * DIM && in_sizes[20] == DIM * DIM
        && in_sizes[22] == NE1 && in_sizes[23] == NE1
        && in_sizes[24] == NE2 && in_sizes[25] == NE2 && in_sizes[26] == NE1;
    if (!sizes_ok) {
        size_t n = (size_t)out_size;
        fill16_kernel<<<(int)((n + 255) / 256), 256, 0, stream>>>((u16*)d_out, 0x429A, n);
        return;
    }

    // fixed workspace layout
    size_t off_B1   = 64;                                     // B1t: [128][32] bf16 = 8KB
    size_t off_g2   = off_B1 + (size_t)DIM * 32 * 2;
    size_t off_Bt   = off_g2 + DIM * 4;                       // Btg (gate)
    size_t off_Bs1  = off_Bt  + (size_t)DIM * DIM * 2;
    size_t off_Bd1  = off_Bs1 + (size_t)DIM * DIM * 2;
    size_t off_Bs2  = off_Bd1 + (size_t)DIM * DIM * 2;
    size_t off_Bd2  = off_Bs2 + (size_t)DIM * DIM * 2;
    size_t off_Bod  = off_Bd2 + (size_t)DIM * DIM * 2;
    size_t off_Bos  = off_Bod + (size_t)DIM * DIM * 2;
    size_t off_Xs   = off_Bos + (size_t)DIM * DIM * 2;
    size_t off_Xd   = off_Xs + (size_t)ND * DIM * 2;
    size_t off_sb   = off_Xd + (size_t)ND * DIM * 2;
    size_t off_aggr = off_sb + (size_t)ND * NH * 4;
    size_t off_cnt  = off_aggr + (size_t)ND * DIM * 4;
    size_t off_offs = off_cnt + (size_t)(ND + 16) * 4;
    size_t off_chk  = off_offs + (size_t)(ND + 16) * 4;
    size_t off_p1   = off_chk + 512;
    size_t off_p2   = off_p1 + (size_t)NE1 * 4;
    size_t off_gate = (off_p2 + (size_t)NE2 * 4 + 255) & ~(size_t)255;
    if (ws_size < off_gate) {
        size_t n = (size_t)out_size;
        fill16_kernel<<<(int)((n + 255) / 256), 256, 0, stream>>>((u16*)d_out, 0x42F6, n);
        return;
    }

    // gate-buffer chunking for L3 residency: prefer 32MB chunks (8192 tiles x 16 x 256B)
    // so {gates chunk + Xs/Xd + aggr} stays well under the 256MB Infinity Cache.
    // Fall back to smaller chunks if workspace is tight.
    int cpp = 8192;
    while (cpp >= 1024 && off_gate + (size_t)cpp * 16 * 256 > ws_size) cpp >>= 1;
    if (off_gate + (size_t)cpp * 16 * 256 > ws_size) {
        size_t n = (size_t)out_size;
        fill16_kernel<<<(int)((n + 255) / 256), 256, 0, stream>>>((u16*)d_out, 0x42F6, n);
        return;
    }
    int nparts = (NT1 + cpp - 1) / cpp;

    char* w = (char*)d_ws;
    int*   flag = (int*)w;
    u16*   B1t  = (u16*)(w + off_B1);
    float* gb2p = (float*)(w + off_g2);
    u16*   Btg  = (u16*)(w + off_Bt);
    u16*   Bs1  = (u16*)(w + off_Bs1);
    u16*   Bd1  = (u16*)(w + off_Bd1);
    u16*   Bs2  = (u16*)(w + off_Bs2);
    u16*   Bd2  = (u16*)(w + off_Bd2);
    u16*   Bod  = (u16*)(w + off_Bod);
    u16*   Bos  = (u16*)(w + off_Bos);
    bf16*  Xs   = (bf16*)(w + off_Xs);
    bf16*  Xd   = (bf16*)(w + off_Xd);
    float* sb   = (float*)(w + off_sb);
    float* aggr = (float*)(w + off_aggr);
    u32*   cnt  = (u32*)(w + off_cnt);
    u32*   offs = (u32*)(w + off_offs);
    u32*   chk  = (u32*)(w + off_chk);
    u32*   perm1 = (u32*)(w + off_p1);
    u32*   perm2 = (u32*)(w + off_p2);
    u32*   gates = (u32*)(w + off_gate);

    detect_kernel<<<1, 64, 0, stream>>>((const u16*)W_src1, flag);
    prep_kernel<<<64, 256, 0, stream>>>(flag, emb1, gW1, gb1, gW2, gb2,
                                        W_src1, W_dst1, W_src2, W_dst2, Wo_drug, Wo_dis,
                                        B1t, gb2p, Btg, Bs1, Bd1, Bs2, Bd2, Bod, Bos);

    // sort e1 by dst
    hipMemsetAsync(cnt, 0, (size_t)(ND + 16) * 4, stream);
    hist_kernel<<<1024, 256, 0, stream>>>(e1_dst, NE1, cnt);
    scanA_kernel<<<98, 256, 0, stream>>>(cnt, ND, chk);
    scanB_kernel<<<1, 256, 0, stream>>>(chk, 98);
    scanC_kernel<<<98, 256, 0, stream>>>(cnt, ND, chk, offs);
    scatter_kernel<<<1024, 256, 0, stream>>>(e1_dst, NE1, offs, perm1);

    // phase 1: drug -> drug (gated)
    hipMemsetAsync(sb, 0, (size_t)ND * NH * 4, stream);
    hipMemsetAsync(aggr, 0, (size_t)ND * DIM * 4, stream);
    proj2m_kernel<<<GRID_M, 256, 0, stream>>>(flag, x_drug, b_src1, b_dst1, Bs1, Bd1, Xs, Xd, ND);
    for (int part = 0; part < nparts; ++part) {
        int c0 = part * cpp, c1 = c0 + cpp;
        if (c1 > NT1) c1 = NT1;
        if (c0 >= c1) break;
        gateall_kernel<<<GRID_G, 256, 0, stream>>>(flag, e1_cat, e1_cont,
                                                   gb2p, B1t, Btg, perm1, gates, c0, c1);
        edge1e_kernel<<<GRID_E1, 256, 0, stream>>>(flag, Xs, Xd, e1_src, e1_dst,
                                                   attn1, perm1, gates, c0, c1, sb, aggr);
    }
    projoutm_kernel<<<GRID_M, 256, 0, stream>>>(flag, aggr, sb, bo_drug, Bod, d_out, 0, ND);

    // sort e2 by dst
    hipMemsetAsync(cnt, 0, (size_t)(NS + 16) * 4, stream);
    hist_kernel<<<1024, 256, 0, stream>>>(e2_dst, NE2, cnt);
    scanA_kernel<<<49, 256, 0, stream>>>(cnt, NS, chk);
    scanB_kernel<<<1, 256, 0, stream>>>(chk, 49);
    scanC_kernel<<<49, 256, 0, stream>>>(cnt, NS, chk, offs);
    scatter_kernel<<<1024, 256, 0, stream>>>(e2_dst, NE2, offs, perm2);

    // phase 2: drug -> disease (no gate)
    hipMemsetAsync(sb, 0, (size_t)NS * NH * 4, stream);
    hipMemsetAsync(aggr, 0, (size_t)NS * DIM * 4, stream);
    proj1m_kernel<<<GRID_M, 256, 0, stream>>>(flag, x_drug, b_src2, Bs2, Xs, ND);
    proj1m_kernel<<<GRID_M, 256, 0, stream>>>(flag, x_dis, b_dst2, Bd2, Xd, NS);
    edge2e_kernel<<<GRID_E2, 256, 0, stream>>>(flag, Xs, Xd, e2_src, e2_dst, attn2, perm2, sb, aggr);
    projoutm_kernel<<<GRID_M, 256, 0, stream>>>(flag, aggr, sb, bo_dis, Bos, d_out, (size_t)ND * DIM, NS);
}

// Round 11
// 733.452 us; speedup vs baseline: 1.0746x; 1.0746x over previous
//
#include <hip/hip_runtime.h>
#include <hip/hip_bf16.h>
#include <math.h>

#define ND 100000
#define NS 50000
#define NE1 500000
#define NE2 250000
#define DIM 128
#define NH 4
#define HDI 32
#define GRID_M 512    // MFMA proj kernels: 2048 waves
#define GRID_G 2048   // gateall: 8192 waves
#define GRID_E1 2048  // edge1e: 8192 waves
#define GRID_E2 2048  // edge2e: 8192 waves
#define NT1 (NE1 / 16)  // 31250 sorted 16-edge chunks
#define NT2 (NE2 / 16)  // 15625

typedef __hip_bfloat16 bf16;
typedef unsigned short u16;
typedef unsigned int u32;
typedef short sx8 __attribute__((ext_vector_type(8)));   // 8 bf16 MFMA A/B frag
typedef float fx4 __attribute__((ext_vector_type(4)));   // MFMA C/D frag

__device__ __forceinline__ float ldf(const float* p, size_t i) { return p[i]; }
__device__ __forceinline__ float ldf(const bf16* p, size_t i) { return __bfloat162float(p[i]); }
__device__ __forceinline__ float b2f(bf16 v) { return __bfloat162float(v); }

__device__ __forceinline__ u16 f2bfu(float f) {
    __hip_bfloat16 h = __float2bfloat16(f);
    union { __hip_bfloat16 b; u16 u; } c; c.b = h; return c.u;
}
// unpack a bf16 pair (one dword, little-endian) to two floats
__device__ __forceinline__ float2 bfp(u32 u) {
    float2 r;
    r.x = __uint_as_float(u << 16);
    r.y = __uint_as_float(u & 0xffff0000u);
    return r;
}
__device__ __forceinline__ sx8 pack8(float4 v0, float4 v1) {
    sx8 r;
    r[0] = (short)f2bfu(v0.x); r[1] = (short)f2bfu(v0.y);
    r[2] = (short)f2bfu(v0.z); r[3] = (short)f2bfu(v0.w);
    r[4] = (short)f2bfu(v1.x); r[5] = (short)f2bfu(v1.y);
    r[6] = (short)f2bfu(v1.z); r[7] = (short)f2bfu(v1.w);
    return r;
}
// A-fragment load: 8 consecutive input elems -> bf16x8
__device__ __forceinline__ sx8 lda8(const bf16* p) { return *(const sx8*)p; }
__device__ __forceinline__ sx8 lda8(const float* p) {
    return pack8(*(const float4*)p, *(const float4*)(p + 4));
}
// 4 consecutive values as float4
__device__ __forceinline__ float4 ld4(const float* p) { return *(const float4*)p; }
__device__ __forceinline__ float4 ld4(const bf16* p) {
    float2 a = bfp(*(const u32*)p);
    float2 b = bfp(*(const u32*)(p + 2));
    return make_float4(a.x, a.y, b.x, b.y);
}

// ---------- fast transcendentals (native v_exp/v_rcp; ~1-2 ulp) ----------
__device__ __forceinline__ float gelu_fast(float x) {
    float u2 = x * fmaf(x * x, 0.0713550f, 1.5957691f);
    u2 = fminf(u2, 40.0f);
    float t = __expf(u2);
    return x * t * __builtin_amdgcn_rcpf(t + 1.0f);
}
__device__ __forceinline__ float sigmoid_fast(float x) {
    return __builtin_amdgcn_rcpf(1.0f + __expf(-x));
}
__device__ __forceinline__ float exp_fast(float x) { return __expf(x); }

// ---------- per-wave LDS slab helpers (16 rows x 128 dims f32, XOR-swizzled) ----------
__device__ __forceinline__ void slab_store(float* Gw, const fx4* acc, int er, int lg) {
#pragma unroll
    for (int f = 0; f < 8; ++f)
#pragma unroll
        for (int r = 0; r < 4; ++r) {
            int row = 4 * lg + r;
            int byo = row * 512 + (((16 * f + er) * 4) ^ ((row & 7) << 4));
            *(float*)((char*)Gw + byo) = acc[f][r];
        }
}
__device__ __forceinline__ void slab_flush_bf16(const float* Gw, int lane, bf16* Yrow) {
#pragma unroll
    for (int i = 0; i < 16; ++i) {
        float2 gv = *(const float2*)((const char*)Gw + i * 512 + ((lane * 8) ^ ((i & 7) << 4)));
        u32 pk = ((u32)f2bfu(gv.y) << 16) | (u32)f2bfu(gv.x);
        *(u32*)&Yrow[(size_t)i * DIM + 2 * lane] = pk;
    }
}
__device__ __forceinline__ void sty2(float* p, float2 v) { *(float2*)p = v; }
__device__ __forceinline__ void sty2(bf16* p, float2 v) {
    *(u32*)p = ((u32)f2bfu(v.y) << 16) | (u32)f2bfu(v.x);
}

// ---------- diagnostics ----------
__global__ void fill16_kernel(u16* p, u16 v, size_t n) {
    size_t i = (size_t)blockIdx.x * blockDim.x + threadIdx.x;
    if (i < n) p[i] = v;
}

__global__ __launch_bounds__(64) void detect_kernel(const u16* w, int* flag) {
    int lane = threadIdx.x;
    int mx = 0;
    for (int j = 0; j < 32; ++j) {
        int i = 2 * (lane + 64 * j);
        int e = (w[i] >> 7) & 0xFF;
        mx = mx > e ? mx : e;
    }
    for (int d = 32; d; d >>= 1) { int o = __shfl_xor(mx, d); mx = mx > o ? mx : o; }
    if (lane == 0) flag[0] = (mx >= 0x90) ? 1 : 0;
}

// ---------- counting sort by dst ----------
__global__ __launch_bounds__(256) void hist_kernel(const int* __restrict__ dst, int ne,
                                                   u32* __restrict__ cnt) {
    int stride = gridDim.x * blockDim.x;
    for (int i = blockIdx.x * blockDim.x + threadIdx.x; i < ne; i += stride)
        atomicAdd(&cnt[dst[i]], 1u);
}

__global__ __launch_bounds__(256) void scanA_kernel(const u32* __restrict__ cnt, int nb,
                                                    u32* __restrict__ chk) {
    __shared__ u32 ws[4];
    int b = blockIdx.x, t = threadIdx.x;
    int i0 = b * 1024 + t * 4;
    u32 s = 0;
#pragma unroll
    for (int j = 0; j < 4; ++j) { int i = i0 + j; if (i < nb) s += cnt[i]; }
#pragma unroll
    for (int d = 1; d < 64; d <<= 1) s += __shfl_xor(s, d);
    if ((t & 63) == 0) ws[t >> 6] = s;
    __syncthreads();
    if (t == 0) chk[b] = ws[0] + ws[1] + ws[2] + ws[3];
}

__global__ __launch_bounds__(256) void scanB_kernel(u32* __restrict__ chk, int nc) {
    __shared__ u32 sh[256];
    int t = threadIdx.x;
    u32 v = (t < nc) ? chk[t] : 0u;
    sh[t] = v;
    __syncthreads();
    for (int d = 1; d < 256; d <<= 1) {
        u32 x = (t >= d) ? sh[t - d] : 0u;
        __syncthreads();
        if (t >= d) sh[t] += x;
        __syncthreads();
    }
    if (t < nc) chk[t] = sh[t] - v;
}

__global__ __launch_bounds__(256) void scanC_kernel(const u32* __restrict__ cnt, int nb,
                                                    const u32* __restrict__ chk,
                                                    u32* __restrict__ offs) {
    __shared__ u32 wsum[4];
    int b = blockIdx.x, t = threadIdx.x, lane = t & 63, wv = t >> 6;
    int i0 = b * 1024 + t * 4;
    u32 c0 = (i0 + 0 < nb) ? cnt[i0 + 0] : 0u;
    u32 c1 = (i0 + 1 < nb) ? cnt[i0 + 1] : 0u;
    u32 c2 = (i0 + 2 < nb) ? cnt[i0 + 2] : 0u;
    u32 c3 = (i0 + 3 < nb) ? cnt[i0 + 3] : 0u;
    u32 tot = c0 + c1 + c2 + c3;
    u32 inc = tot;
#pragma unroll
    for (int d = 1; d < 64; d <<= 1) { u32 x = __shfl_up(inc, d); if (lane >= d) inc += x; }
    if (lane == 63) wsum[wv] = inc;
    __syncthreads();
    u32 base = chk[b] + (inc - tot);
    for (int k = 0; k < wv; ++k) base += wsum[k];
    if (i0 + 0 < nb) offs[i0 + 0] = base;
    if (i0 + 1 < nb) offs[i0 + 1] = base + c0;
    if (i0 + 2 < nb) offs[i0 + 2] = base + c0 + c1;
    if (i0 + 3 < nb) offs[i0 + 3] = base + c0 + c1 + c2;
}

__global__ __launch_bounds__(256) void scatter_kernel(const int* __restrict__ dst, int ne,
                                                      u32* __restrict__ offs,
                                                      u32* __restrict__ perm) {
    int stride = gridDim.x * blockDim.x;
    for (int i = blockIdx.x * blockDim.x + threadIdx.x; i < ne; i += stride) {
        u32 p = atomicAdd(&offs[dst[i]], 1u);
        perm[p] = (u32)i;
    }
}

// ---------- prep: bf16 transposed weight tables + gate-MLP constants ----------
template <typename T>
__device__ __forceinline__ void transp(const T* W, u16* Bt, int gtid, int gstride) {
    for (int i = gtid; i < DIM * DIM; i += gstride) {
        int n = i >> 7, k = i & 127;
        Bt[i] = f2bfu(ldf(W, (size_t)k * DIM + n));
    }
}

// B1t[n][k] (n=0..127, k=0..31): k<8 -> gb1[n] + emb[k]@gW1[:32,n] (onehot-cat path);
// 8<=k<12 -> gW1[32+(k-8)][n] (cont path); else 0. GEMM1 becomes one K=32 MFMA.
template <typename T>
__device__ __forceinline__ void prep_body(
    const T* emb, const T* gW1, const T* gb1, const T* gW2,
    const T* Ws1, const T* Wd1, const T* Ws2, const T* Wd2, const T* Wod, const T* Wos,
    u16* B1t, float* gb2f, const T* gb2,
    u16* Btg, u16* Bs1, u16* Bd1, u16* Bs2, u16* Bd2, u16* Bod, u16* Bos)
{
    int gtid = blockIdx.x * blockDim.x + threadIdx.x;
    int gstride = gridDim.x * blockDim.x;
    for (int i = gtid; i < DIM * 32; i += gstride) {
        int n = i >> 5, k = i & 31;
        float v = 0.0f;
        if (k < 8) {
            v = ldf(gb1, n);
            for (int q = 0; q < 32; ++q) v += ldf(emb, k * 32 + q) * ldf(gW1, (size_t)q * DIM + n);
        } else if (k < 12) {
            v = ldf(gW1, (size_t)(32 + (k - 8)) * DIM + n);
        }
        B1t[i] = f2bfu(v);
    }
    for (int i = gtid; i < DIM; i += gstride) gb2f[i] = ldf(gb2, i);
    transp(gW2, Btg, gtid, gstride);
    transp(Ws1, Bs1, gtid, gstride);
    transp(Wd1, Bd1, gtid, gstride);
    transp(Ws2, Bs2, gtid, gstride);
    transp(Wd2, Bd2, gtid, gstride);
    transp(Wod, Bod, gtid, gstride);
    transp(Wos, Bos, gtid, gstride);
}

__global__ __launch_bounds__(256) void prep_kernel(
    const int* __restrict__ flag,
    const void* emb, const void* gW1, const void* gb1, const void* gW2, const void* gb2,
    const void* Ws1, const void* Wd1, const void* Ws2, const void* Wd2,
    const void* Wod, const void* Wos,
    u16* __restrict__ B1t, float* __restrict__ gb2f,
    u16* __restrict__ Btg, u16* __restrict__ Bs1, u16* __restrict__ Bd1,
    u16* __restrict__ Bs2, u16* __restrict__ Bd2, u16* __restrict__ Bod,
    u16* __restrict__ Bos)
{
    if (flag[0])
        prep_body((const float*)emb, (const float*)gW1, (const float*)gb1, (const float*)gW2,
                  (const float*)Ws1, (const float*)Wd1, (const float*)Ws2, (const float*)Wd2,
                  (const float*)Wod, (const float*)Wos,
                  B1t, gb2f, (const float*)gb2, Btg, Bs1, Bd1, Bs2, Bd2, Bod, Bos);
    else
        prep_body((const bf16*)emb, (const bf16*)gW1, (const bf16*)gb1, (const bf16*)gW2,
                  (const bf16*)Ws1, (const bf16*)Wd1, (const bf16*)Ws2, (const bf16*)Wd2,
                  (const bf16*)Wod, (const bf16*)Wos,
                  B1t, gb2f, (const bf16*)gb2, Btg, Bs1, Bd1, Bs2, Bd2, Bod, Bos);
}

// ---------- MFMA node projections: wave per 16-node tile ----------
template <typename T>
__device__ __forceinline__ void proj2m_body(
    float* Gw, const T* X, const T* b1, const T* b2,
    const u16* Bt1, const u16* Bt2, bf16* Y1, bf16* Y2, int N)
{
    int tid = threadIdx.x, lane = tid & 63, er = lane & 15, lg = lane >> 4;
    float c1i[8], c2i[8];
#pragma unroll
    for (int f = 0; f < 8; ++f) {
        c1i[f] = ldf(b1, 16 * f + er);
        c2i[f] = ldf(b2, 16 * f + er);
    }
    const int NW = GRID_M * 4;
    int gwid = blockIdx.x * 4 + (tid >> 6);
    int tiles = N / 16;
    for (int t = gwid; t < tiles; t += NW) {
        const T* xr = X + (size_t)(t * 16 + er) * DIM;
        sx8 a[4];
#pragma unroll
        for (int ks = 0; ks < 4; ++ks) a[ks] = lda8(xr + ks * 32 + lg * 8);
        fx4 acc1[8], acc2[8];
#pragma unroll
        for (int f = 0; f < 8; ++f) {
            acc1[f][0] = c1i[f]; acc1[f][1] = c1i[f]; acc1[f][2] = c1i[f]; acc1[f][3] = c1i[f];
            acc2[f][0] = c2i[f]; acc2[f][1] = c2i[f]; acc2[f][2] = c2i[f]; acc2[f][3] = c2i[f];
        }
#pragma unroll
        for (int ks = 0; ks < 4; ++ks)
#pragma unroll
            for (int f = 0; f < 8; ++f) {
                sx8 bv1 = *(const sx8*)(Bt1 + (size_t)(16 * f + er) * DIM + ks * 32 + lg * 8);
                acc1[f] = __builtin_amdgcn_mfma_f32_16x16x32_bf16(a[ks], bv1, acc1[f], 0, 0, 0);
                sx8 bv2 = *(const sx8*)(Bt2 + (size_t)(16 * f + er) * DIM + ks * 32 + lg * 8);
                acc2[f] = __builtin_amdgcn_mfma_f32_16x16x32_bf16(a[ks], bv2, acc2[f], 0, 0, 0);
            }
        slab_store(Gw, acc1, er, lg);
        slab_flush_bf16(Gw, lane, Y1 + (size_t)t * 16 * DIM);
        slab_store(Gw, acc2, er, lg);
        slab_flush_bf16(Gw, lane, Y2 + (size_t)t * 16 * DIM);
    }
}

__global__ __launch_bounds__(256) void proj2m_kernel(
    const int* __restrict__ flag, const void* X, const void* b1, const void* b2,
    const u16* __restrict__ Bt1, const u16* __restrict__ Bt2,
    bf16* __restrict__ Y1, bf16* __restrict__ Y2, int N)
{
    __shared__ float Gt[4][16 * 128];
    float* Gw = Gt[threadIdx.x >> 6];
    if (flag[0]) proj2m_body(Gw, (const float*)X, (const float*)b1, (const float*)b2, Bt1, Bt2, Y1, Y2, N);
    else         proj2m_body(Gw, (const bf16*)X, (const bf16*)b1, (const bf16*)b2, Bt1, Bt2, Y1, Y2, N);
}

template <typename T>
__device__ __forceinline__ void proj1m_body(
    float* Gw, const T* X, const T* b, const u16* Bt, bf16* Y, int N)
{
    int tid = threadIdx.x, lane = tid & 63, er = lane & 15, lg = lane >> 4;
    float ci[8];
#pragma unroll
    for (int f = 0; f < 8; ++f) ci[f] = ldf(b, 16 * f + er);
    const int NW = GRID_M * 4;
    int gwid = blockIdx.x * 4 + (tid >> 6);
    int tiles = N / 16;
    for (int t = gwid; t < tiles; t += NW) {
        const T* xr = X + (size_t)(t * 16 + er) * DIM;
        sx8 a[4];
#pragma unroll
        for (int ks = 0; ks < 4; ++ks) a[ks] = lda8(xr + ks * 32 + lg * 8);
        fx4 acc[8];
#pragma unroll
        for (int f = 0; f < 8; ++f) {
            acc[f][0] = ci[f]; acc[f][1] = ci[f]; acc[f][2] = ci[f]; acc[f][3] = ci[f];
        }
#pragma unroll
        for (int ks = 0; ks < 4; ++ks)
#pragma unroll
            for (int f = 0; f < 8; ++f) {
                sx8 bv = *(const sx8*)(Bt + (size_t)(16 * f + er) * DIM + ks * 32 + lg * 8);
                acc[f] = __builtin_amdgcn_mfma_f32_16x16x32_bf16(a[ks], bv, acc[f], 0, 0, 0);
            }
        slab_store(Gw, acc, er, lg);
        slab_flush_bf16(Gw, lane, Y + (size_t)t * 16 * DIM);
    }
}

__global__ __launch_bounds__(256) void proj1m_kernel(
    const int* __restrict__ flag, const void* X, const void* b,
    const u16* __restrict__ Bt, bf16* __restrict__ Y, int N)
{
    __shared__ float Gt[4][16 * 128];
    float* Gw = Gt[threadIdx.x >> 6];
    if (flag[0]) proj1m_body(Gw, (const float*)X, (const float*)b, Bt, Y, N);
    else         proj1m_body(Gw, (const bf16*)X, (const bf16*)b, Bt, Y, N);
}

// out[n] = (A[n] / s[n,head]) @ W + b  — division folded into A-fragment load
template <typename T>
__device__ __forceinline__ void projoutm_body(
    float* Gw, const float* A, const float* s, const T* b,
    const u16* Bt, T* out, int N)
{
    int tid = threadIdx.x, lane = tid & 63, er = lane & 15, lg = lane >> 4;
    float ci[8];
#pragma unroll
    for (int f = 0; f < 8; ++f) ci[f] = ldf(b, 16 * f + er);
    const int NW = GRID_M * 4;
    int gwid = blockIdx.x * 4 + (tid >> 6);
    int tiles = N / 16;
    for (int t = gwid; t < tiles; t += NW) {
        const float* ar = A + (size_t)(t * 16 + er) * DIM;
        const float* sr = s + (size_t)(t * 16 + er) * NH;
        sx8 a[4];
#pragma unroll
        for (int ks = 0; ks < 4; ++ks) {
            float inv = 1.0f / (sr[ks] + 1e-16f);   // head == ks for this k-range
            float4 v0 = *(const float4*)(ar + ks * 32 + lg * 8);
            float4 v1 = *(const float4*)(ar + ks * 32 + lg * 8 + 4);
            v0.x *= inv; v0.y *= inv; v0.z *= inv; v0.w *= inv;
            v1.x *= inv; v1.y *= inv; v1.z *= inv; v1.w *= inv;
            a[ks] = pack8(v0, v1);
        }
        fx4 acc[8];
#pragma unroll
        for (int f = 0; f < 8; ++f) {
            acc[f][0] = ci[f]; acc[f][1] = ci[f]; acc[f][2] = ci[f]; acc[f][3] = ci[f];
        }
#pragma unroll
        for (int ks = 0; ks < 4; ++ks)
#pragma unroll
            for (int f = 0; f < 8; ++f) {
                sx8 bv = *(const sx8*)(Bt + (size_t)(16 * f + er) * DIM + ks * 32 + lg * 8);
                acc[f] = __builtin_amdgcn_mfma_f32_16x16x32_bf16(a[ks], bv, acc[f], 0, 0, 0);
            }
        slab_store(Gw, acc, er, lg);
#pragma unroll
        for (int i = 0; i < 16; ++i) {
            float2 gv = *(const float2*)((const char*)Gw + i * 512 + ((lane * 8) ^ ((i & 7) << 4)));
            sty2(out + (size_t)(t * 16 + i) * DIM + 2 * lane, gv);
        }
    }
}

__global__ __launch_bounds__(256) void projoutm_kernel(
    const int* __restrict__ flag, const float* __restrict__ A, const float* __restrict__ s,
    const void* b, const u16* __restrict__ Bt, void* out, size_t off, int N)
{
    __shared__ float Gt[4][16 * 128];
    float* Gw = Gt[threadIdx.x >> 6];
    if (flag[0]) projoutm_body(Gw, A, s, (const float*)b, Bt, (float*)out + off, N);
    else         projoutm_body(Gw, A, s, (const bf16*)b, Bt, (bf16*)out + off, N);
}

// ---------- gate MLP kernel: one-hot MFMA gate + pipelined index prefetch ----------
// R4: no min-waves clamp. R5: no big reg-hoists. R6: no strided LDS tables.
// R7: one-hot MFMA. R8: fusion serializes — split. R9: index-chain prefetch.
// R10 lesson: chunked producer->consumer pairs serialize (788 vs 690) — nparts=1.
// R11: GRID_G doubled (BW scales with wave count on these latency-bound kernels).
template <typename T>
__device__ __forceinline__ void gateall_body(
    float* Gw, const int* cat, const T* econt,
    const float* gb2f, const u16* B1t, const u16* Btg,
    const u32* perm, u32* gates, int c0, int c1)
{
    int tid = threadIdx.x;
    int lane = tid & 63;
    int er = lane & 15, lg = lane >> 4;

    float cinit[8];
#pragma unroll
    for (int f = 0; f < 8; ++f) cinit[f] = gb2f[16 * f + er];

    const int NW = GRID_G * 4;
    int span = c1 - c0;
    int w = blockIdx.x * 4 + (tid >> 6);
    int tpw = (span + NW - 1) / NW;
    int t0 = c0 + w * tpw, t1 = t0 + tpw;
    if (t1 > c1) t1 = c1;

    const fx4 zf = {0.f, 0.f, 0.f, 0.f};

    // preload tile t0's index/feature chain
    int c = 0;
    float4 fv = make_float4(0.f, 0.f, 0.f, 0.f);
    if (t0 < t1) {
        int e = (int)perm[t0 * 16 + er];
        c = cat[e];
        fv = ld4(econt + (size_t)e * 4);
    }

    for (int t = t0; t < t1; ++t) {
        // ---- prefetch tile t+1's chain (completes under this tile's compute) ----
        int tn = t + 1;
        int e_n = (tn < t1) ? (int)perm[tn * 16 + er] : 0;
        int c_n = cat[e_n];
        float4 fv_n = ld4(econt + (size_t)e_n * 4);

        // ---- A1 fragment in registers: [onehot8(cat), f0..f3, 0...] ----
        sx8 a1;
#pragma unroll
        for (int j = 0; j < 8; ++j) a1[j] = 0;
        if (lg == 0) {
#pragma unroll
            for (int j = 0; j < 8; ++j) a1[j] = (c == j) ? (short)0x3F80 : (short)0;
        } else if (lg == 1) {
            a1[0] = (short)f2bfu(fv.x); a1[1] = (short)f2bfu(fv.y);
            a1[2] = (short)f2bfu(fv.z); a1[3] = (short)f2bfu(fv.w);
        }

        // ---- GEMM1 on MFMA (K=32) ----
        fx4 p1[8];
#pragma unroll
        for (int f = 0; f < 8; ++f) {
            sx8 b1 = *(const sx8*)(B1t + (size_t)(16 * f + er) * 32 + lg * 8);
            p1[f] = __builtin_amdgcn_mfma_f32_16x16x32_bf16(a1, b1, zf, 0, 0, 0);
        }

        // ---- gelu -> swizzled slab (row=edge 4lg+r, col=dim 16f+er) ----
#pragma unroll
        for (int f = 0; f < 8; ++f)
#pragma unroll
            for (int r = 0; r < 4; ++r) {
                int row = 4 * lg + r;
                float hg = gelu_fast(p1[f][r]);
                int byo = row * 512 + (((16 * f + er) * 4) ^ ((row & 7) << 4));
                *(float*)((char*)Gw + byo) = hg;
            }

        // ---- read back h as GEMM2 A-fragments (row=er, dims ks*32+lg*8..+7) ----
        sx8 a2[4];
#pragma unroll
        for (int ks = 0; ks < 4; ++ks) {
            int base = ks * 128 + lg * 32;
            float4 v0 = *(const float4*)((const char*)Gw + er * 512 + ((base)      ^ ((er & 7) << 4)));
            float4 v1 = *(const float4*)((const char*)Gw + er * 512 + ((base + 16) ^ ((er & 7) << 4)));
            a2[ks] = pack8(v0, v1);
        }

        // ---- GEMM2 on MFMA ----
        fx4 acc[8];
#pragma unroll
        for (int f = 0; f < 8; ++f) {
            acc[f][0] = cinit[f]; acc[f][1] = cinit[f];
            acc[f][2] = cinit[f]; acc[f][3] = cinit[f];
        }
#pragma unroll
        for (int ks = 0; ks < 4; ++ks) {
#pragma unroll
            for (int f = 0; f < 8; ++f) {
                sx8 b = *(const sx8*)(Btg + (size_t)(16 * f + er) * DIM + ks * 32 + lg * 8);
                acc[f] = __builtin_amdgcn_mfma_f32_16x16x32_bf16(a2[ks], b, acc[f], 0, 0, 0);
            }
        }

        // ---- sigmoid -> slab ----
#pragma unroll
        for (int f = 0; f < 8; ++f)
#pragma unroll
            for (int r = 0; r < 4; ++r) {
                int row = 4 * lg + r;
                float g = sigmoid_fast(acc[f][r]);
                int byo = row * 512 + (((16 * f + er) * 4) ^ ((row & 7) << 4));
                *(float*)((char*)Gw + byo) = g;
            }

        // ---- pack bf16 pairs; coalesced 256B per edge, sorted-order index ----
#pragma unroll
        for (int i = 0; i < 16; ++i) {
            float2 gv = *(const float2*)((const char*)Gw + i * 512 + ((lane * 8) ^ ((i & 7) << 4)));
            u32 pk = ((u32)f2bfu(gv.y) << 16) | (u32)f2bfu(gv.x);
            gates[((size_t)(t - c0) * 16 + i) * 64 + lane] = pk;
        }

        c = c_n; fv = fv_n;
    }
}

__global__ __launch_bounds__(256) void gateall_kernel(
    const int* __restrict__ flag, const int* __restrict__ cat, const void* econt,
    const float* __restrict__ gb2f, const u16* __restrict__ B1t,
    const u16* __restrict__ Btg,
    const u32* __restrict__ perm, u32* __restrict__ gates, int c0, int c1)
{
    __shared__ float Gt[4][16 * 128];   // 32 KB
    float* Gw = Gt[threadIdx.x >> 6];
    if (flag[0]) gateall_body(Gw, cat, (const float*)econt, gb2f, B1t, Btg, perm, gates, c0, c1);
    else         gateall_body(Gw, cat, (const bf16*)econt, gb2f, B1t, Btg, perm, gates, c0, c1);
}

// ---------- edge1 epilogue: depth-2 pipelined gathers + index chain ----------
// R11: tile t's 48 gathers are issued one iteration AHEAD (during t-1's compute), so
// compute never waits on a fresh gather burst; index chain runs two tiles ahead.
template <typename T>
__device__ __forceinline__ void edge1e_body(
    const bf16* Xs, const bf16* Xd,
    const int* src, const int* dst,
    const T* attn, const u32* perm, const u32* gates, int c0, int c1,
    float* s_out, float* aggr)
{
    int tid = threadIdx.x;
    int lane = tid & 63;
    int d0 = 2 * lane, h = lane >> 4, k0 = d0 & 31;
    float av0 = ldf(attn, h * HDI + k0), av1 = ldf(attn, h * HDI + k0 + 1);
    const float rs = 0.17677669529663688110f;

    const int NW = GRID_E1 * 4;
    int span = c1 - c0;
    int w = blockIdx.x * 4 + (tid >> 6);
    int cpw = (span + NW - 1) / NW;
    int t0 = c0 + w * cpw, t1 = t0 + cpw;
    if (t1 > c1) t1 = c1;
    if (t0 >= t1) return;

    int cur_di = -1;
    float acc0 = 0.f, acc1 = 0.f, ssum = 0.f;

    // prologue: idx(t0) -> gathers(t0); idx(t0+1)
    u32 svA = 0, dvA = 0;
    if (lane < 16) {
        u32 pe = perm[t0 * 16 + lane];
        svA = (u32)src[(int)pe];
        dvA = (u32)dst[(int)pe];
    }
    u32 xspA[16], xdpA[16], gpA[16];
#pragma unroll
    for (int i = 0; i < 16; ++i) {
        int si = (int)__builtin_amdgcn_readlane(svA, i);
        int di = (int)__builtin_amdgcn_readlane(dvA, i);
        xspA[i] = *(const u32*)&Xs[(size_t)si * DIM + d0];
        xdpA[i] = *(const u32*)&Xd[(size_t)di * DIM + d0];
        gpA[i]  = gates[((size_t)(t0 - c0) * 16 + i) * 64 + lane];
    }
    u32 svB = 0, dvB = 0;
    if (t0 + 1 < t1 && lane < 16) {
        u32 pe = perm[(t0 + 1) * 16 + lane];
        svB = (u32)src[(int)pe];
        dvB = (u32)dst[(int)pe];
    }

    for (int t = t0; t < t1; ++t) {
        // issue gathers for tile t+1 from in-flight idx chain
        u32 xspB[16], xdpB[16], gpB[16];
        if (t + 1 < t1) {
#pragma unroll
            for (int i = 0; i < 16; ++i) {
                int si = (int)__builtin_amdgcn_readlane(svB, i);
                int di = (int)__builtin_amdgcn_readlane(dvB, i);
                xspB[i] = *(const u32*)&Xs[(size_t)si * DIM + d0];
                xdpB[i] = *(const u32*)&Xd[(size_t)di * DIM + d0];
                gpB[i]  = gates[((size_t)(t + 1 - c0) * 16 + i) * 64 + lane];
            }
        }
        // idx chain for tile t+2 (no wait)
        u32 svC = 0, dvC = 0;
        if (t + 2 < t1 && lane < 16) {
            u32 pe = perm[(t + 2) * 16 + lane];
            svC = (u32)src[(int)pe];
            dvC = (u32)dst[(int)pe];
        }

        // compute epilogue(t) from A buffers (issued last iteration -> already landed)
#pragma unroll
        for (int i = 0; i < 16; ++i) {
            int di = (int)__builtin_amdgcn_readlane(dvA, i);
            float2 sxy = bfp(xspA[i]);
            float2 dxy = bfp(xdpA[i]);
            float2 gxy = bfp(gpA[i]);
            if (di != cur_di) {
                if (cur_di >= 0) {
                    float* ap = &aggr[(size_t)cur_di * DIM + d0];
                    atomicAdd(ap, acc0);
                    atomicAdd(ap + 1, acc1);
                    if ((lane & 15) == 0)
                        atomicAdd(&s_out[(size_t)cur_di * NH + h], ssum);
                }
                cur_di = di; acc0 = 0.f; acc1 = 0.f; ssum = 0.f;
            }
            float m0 = (sxy.x + dxy.x) * gxy.x;
            float m1 = (sxy.y + dxy.y) * gxy.y;
            float p = (sxy.x * dxy.x + sxy.y * dxy.y) * rs + m0 * av0 + m1 * av1;
            p += __shfl_xor(p, 8);
            p += __shfl_xor(p, 4);
            p += __shfl_xor(p, 2);
            p += __shfl_xor(p, 1);
            float ev = exp_fast(fminf(p, 80.0f));
            acc0 = fmaf(ev, m0, acc0);
            acc1 = fmaf(ev, m1, acc1);
            ssum += ev;
        }

        // rotate pipeline buffers
        svA = svB; dvA = dvB; svB = svC; dvB = dvC;
#pragma unroll
        for (int i = 0; i < 16; ++i) {
            xspA[i] = xspB[i]; xdpA[i] = xdpB[i]; gpA[i] = gpB[i];
        }
    }
    if (cur_di >= 0) {
        float* ap = &aggr[(size_t)cur_di * DIM + d0];
        atomicAdd(ap, acc0);
        atomicAdd(ap + 1, acc1);
        if ((lane & 15) == 0)
            atomicAdd(&s_out[(size_t)cur_di * NH + h], ssum);
    }
}

__global__ __launch_bounds__(256) void edge1e_kernel(
    const int* __restrict__ flag,
    const bf16* __restrict__ Xs, const bf16* __restrict__ Xd,
    const int* __restrict__ src, const int* __restrict__ dst,
    const void* attn, const u32* __restrict__ perm, const u32* __restrict__ gates,
    int c0, int c1, float* __restrict__ s_out, float* __restrict__ aggr)
{
    if (flag[0]) edge1e_body(Xs, Xd, src, dst, (const float*)attn, perm, gates, c0, c1, s_out, aggr);
    else         edge1e_body(Xs, Xd, src, dst, (const bf16*)attn, perm, gates, c0, c1, s_out, aggr);
}

// ---------- edge2 epilogue: depth-2 pipelined gathers + index chain, no gate ----------
template <typename T>
__device__ __forceinline__ void edge2e_body(
    const bf16* Xs, const bf16* Xd,
    const int* src, const int* dst,
    const T* attn, const u32* perm, float* s_out, float* aggr)
{
    int tid = threadIdx.x;
    int lane = tid & 63;
    int d0 = 2 * lane, h = lane >> 4, k0 = d0 & 31;
    float av0 = ldf(attn, h * HDI + k0), av1 = ldf(attn, h * HDI + k0 + 1);
    const float rs = 0.17677669529663688110f;

    const int NW = GRID_E2 * 4;
    int w = blockIdx.x * 4 + (tid >> 6);
    int cpw = (NT2 + NW - 1) / NW;
    int t0 = w * cpw, t1 = t0 + cpw;
    if (t1 > NT2) t1 = NT2;
    if (t0 >= t1) return;

    int cur_di = -1;
    float acc0 = 0.f, acc1 = 0.f, ssum = 0.f;

    u32 svA = 0, dvA = 0;
    if (lane < 16) {
        u32 pe = perm[t0 * 16 + lane];
        svA = (u32)src[(int)pe];
        dvA = (u32)dst[(int)pe];
    }
    u32 xspA[16], xdpA[16];
#pragma unroll
    for (int i = 0; i < 16; ++i) {
        int si = (int)__builtin_amdgcn_readlane(svA, i);
        int di = (int)__builtin_amdgcn_readlane(dvA, i);
        xspA[i] = *(const u32*)&Xs[(size_t)si * DIM + d0];
        xdpA[i] = *(const u32*)&Xd[(size_t)di * DIM + d0];
    }
    u32 svB = 0, dvB = 0;
    if (t0 + 1 < t1 && lane < 16) {
        u32 pe = perm[(t0 + 1) * 16 + lane];
        svB = (u32)src[(int)pe];
        dvB = (u32)dst[(int)pe];
    }

    for (int t = t0; t < t1; ++t) {
        u32 xspB[16], xdpB[16];
        if (t + 1 < t1) {
#pragma unroll
            for (int i = 0; i < 16; ++i) {
                int si = (int)__builtin_amdgcn_readlane(svB, i);
                int di = (int)__builtin_amdgcn_readlane(dvB, i);
                xspB[i] = *(const u32*)&Xs[(size_t)si * DIM + d0];
                xdpB[i] = *(const u32*)&Xd[(size_t)di * DIM + d0];
            }
        }
        u32 svC = 0, dvC = 0;
        if (t + 2 < t1 && lane < 16) {
            u32 pe = perm[(t + 2) * 16 + lane];
            svC = (u32)src[(int)pe];
            dvC = (u32)dst[(int)pe];
        }

#pragma unroll
        for (int i = 0; i < 16; ++i) {
            int di = (int)__builtin_amdgcn_readlane(dvA, i);
            float2 sxy = bfp(xspA[i]);
            float2 dxy = bfp(xdpA[i]);
            if (di != cur_di) {
                if (cur_di >= 0) {
                    float* ap = &aggr[(size_t)cur_di * DIM + d0];
                    atomicAdd(ap, acc0);
                    atomicAdd(ap + 1, acc1);
                    if ((lane & 15) == 0)
                        atomicAdd(&s_out[(size_t)cur_di * NH + h], ssum);
                }
                cur_di = di; acc0 = 0.f; acc1 = 0.f; ssum = 0.f;
            }
            float m0 = sxy.x + dxy.x;
            float m1 = sxy.y + dxy.y;
            float p = (sxy.x * dxy.x + sxy.y * dxy.y) * rs + m0 * av0 + m1 * av1;
            p += __shfl_xor(p, 8);
            p += __shfl_xor(p, 4);
            p += __shfl_xor(p, 2);
            p += __shfl_xor(p, 1);
            float ev = exp_fast(fminf(p, 80.0f));
            acc0 = fmaf(ev, m0, acc0);
            acc1 = fmaf(ev, m1, acc1);
            ssum += ev;
        }

        svA = svB; dvA = dvB; svB = svC; dvB = dvC;
#pragma unroll
        for (int i = 0; i < 16; ++i) { xspA[i] = xspB[i]; xdpA[i] = xdpB[i]; }
    }
    if (cur_di >= 0) {
        float* ap = &aggr[(size_t)cur_di * DIM + d0];
        atomicAdd(ap, acc0);
        atomicAdd(ap + 1, acc1);
        if ((lane & 15) == 0)
            atomicAdd(&s_out[(size_t)cur_di * NH + h], ssum);
    }
}

__global__ __launch_bounds__(256) void edge2e_kernel(
    const int* __restrict__ flag,
    const bf16* __restrict__ Xs, const bf16* __restrict__ Xd,
    const int* __restrict__ src, const int* __restrict__ dst,
    const void* attn, const u32* __restrict__ perm,
    float* __restrict__ s_out, float* __restrict__ aggr)
{
    if (flag[0]) edge2e_body(Xs, Xd, src, dst, (const float*)attn, perm, s_out, aggr);
    else         edge2e_body(Xs, Xd, src, dst, (const bf16*)attn, perm, s_out, aggr);
}

extern "C" void kernel_launch(void* const* d_in, const int* in_sizes, int n_in,
                              void* d_out, int out_size, void* d_ws, size_t ws_size,
                              hipStream_t stream)
{
    const void* x_drug  = d_in[0];
    const void* x_dis   = d_in[1];
    const void* e1_cont = d_in[2];
    const void* W_src1  = d_in[3];
    const void* b_src1  = d_in[4];
    const void* W_dst1  = d_in[5];
    const void* b_dst1  = d_in[6];
    const void* attn1   = d_in[7];
    const void* emb1    = d_in[8];
    const void* gW1     = d_in[9];
    const void* gb1     = d_in[10];
    const void* gW2     = d_in[11];
    const void* gb2     = d_in[12];
    const void* W_src2  = d_in[13];
    const void* b_src2  = d_in[14];
    const void* W_dst2  = d_in[15];
    const void* b_dst2  = d_in[16];
    const void* attn2   = d_in[17];
    const void* Wo_drug = d_in[18];
    const void* bo_drug = d_in[19];
    const void* Wo_dis  = d_in[20];
    const void* bo_dis  = d_in[21];
    const int* e1_src = (const int*)d_in[22];
    const int* e1_dst = (const int*)d_in[23];
    const int* e2_src = (const int*)d_in[24];
    const int* e2_dst = (const int*)d_in[25];
    const int* e1_cat = (const int*)d_in[26];

    bool sizes_ok = (n_in == 27)
        && in_sizes[0] == ND * DIM && in_sizes[1] == NS * DIM
        && in_sizes[2] == NE1 * 4
        && in_sizes[3] == DIM * DIM && in_sizes[4] == DIM
        && in_sizes[5] == DIM * DIM && in_sizes[6] == DIM
        && in_sizes[7] == NH * HDI && in_sizes[8] == 8 * 32
        && in_sizes[9] == 36 * DIM && in_sizes[10] == DIM
        && in_sizes[11] == DIM * DIM && in_sizes[12] == DIM
        && in_sizes[13] == DIM * DIM && in_sizes[17] == NH * HDI
        && in_sizes[18] == DIM * DIM && in_sizes[20] == DIM * DIM
        && in_sizes[22] == NE1 && in_sizes[23] == NE1
        && in_sizes[24] == NE2 && in_sizes[25] == NE2 && in_sizes[26] == NE1;
    if (!sizes_ok) {
        size_t n = (size_t)out_size;
        fill16_kernel<<<(int)((n + 255) / 256), 256, 0, stream>>>((u16*)d_out, 0x429A, n);
        return;
    }

    // fixed workspace layout
    size_t off_B1   = 64;                                     // B1t: [128][32] bf16 = 8KB
    size_t off_g2   = off_B1 + (size_t)DIM * 32 * 2;
    size_t off_Bt   = off_g2 + DIM * 4;                       // Btg (gate)
    size_t off_Bs1  = off_Bt  + (size_t)DIM * DIM * 2;
    size_t off_Bd1  = off_Bs1 + (size_t)DIM * DIM * 2;
    size_t off_Bs2  = off_Bd1 + (size_t)DIM * DIM * 2;
    size_t off_Bd2  = off_Bs2 + (size_t)DIM * DIM * 2;
    size_t off_Bod  = off_Bd2 + (size_t)DIM * DIM * 2;
    size_t off_Bos  = off_Bod + (size_t)DIM * DIM * 2;
    size_t off_Xs   = off_Bos + (size_t)DIM * DIM * 2;
    size_t off_Xd   = off_Xs + (size_t)ND * DIM * 2;
    size_t off_sb   = off_Xd + (size_t)ND * DIM * 2;
    size_t off_aggr = off_sb + (size_t)ND * NH * 4;
    size_t off_cnt  = off_aggr + (size_t)ND * DIM * 4;
    size_t off_offs = off_cnt + (size_t)(ND + 16) * 4;
    size_t off_chk  = off_offs + (size_t)(ND + 16) * 4;
    size_t off_p1   = off_chk + 512;
    size_t off_p2   = off_p1 + (size_t)NE1 * 4;
    size_t off_gate = (off_p2 + (size_t)NE2 * 4 + 255) & ~(size_t)255;
    if (ws_size < off_gate) {
        size_t n = (size_t)out_size;
        fill16_kernel<<<(int)((n + 255) / 256), 256, 0, stream>>>((u16*)d_out, 0x42F6, n);
        return;
    }

    // R10 lesson: nparts=1 (chunking serializes producer/consumer pairs; regressed 100us).
    // Halve only if the workspace can't hold the full 128MB gates buffer.
    int cpp = NT1;
    while (cpp >= 1024 && off_gate + (size_t)cpp * 16 * 256 > ws_size) cpp >>= 1;
    if (off_gate + (size_t)cpp * 16 * 256 > ws_size) {
        size_t n = (size_t)out_size;
        fill16_kernel<<<(int)((n + 255) / 256), 256, 0, stream>>>((u16*)d_out, 0x42F6, n);
        return;
    }
    int nparts = (NT1 + cpp - 1) / cpp;

    char* w = (char*)d_ws;
    int*   flag = (int*)w;
    u16*   B1t  = (u16*)(w + off_B1);
    float* gb2p = (float*)(w + off_g2);
    u16*   Btg  = (u16*)(w + off_Bt);
    u16*   Bs1  = (u16*)(w + off_Bs1);
    u16*   Bd1  = (u16*)(w + off_Bd1);
    u16*   Bs2  = (u16*)(w + off_Bs2);
    u16*   Bd2  = (u16*)(w + off_Bd2);
    u16*   Bod  = (u16*)(w + off_Bod);
    u16*   Bos  = (u16*)(w + off_Bos);
    bf16*  Xs   = (bf16*)(w + off_Xs);
    bf16*  Xd   = (bf16*)(w + off_Xd);
    float* sb   = (float*)(w + off_sb);
    float* aggr = (float*)(w + off_aggr);
    u32*   cnt  = (u32*)(w + off_cnt);
    u32*   offs = (u32*)(w + off_offs);
    u32*   chk  = (u32*)(w + off_chk);
    u32*   perm1 = (u32*)(w + off_p1);
    u32*   perm2 = (u32*)(w + off_p2);
    u32*   gates = (u32*)(w + off_gate);

    detect_kernel<<<1, 64, 0, stream>>>((const u16*)W_src1, flag);
    prep_kernel<<<64, 256, 0, stream>>>(flag, emb1, gW1, gb1, gW2, gb2,
                                        W_src1, W_dst1, W_src2, W_dst2, Wo_drug, Wo_dis,
                                        B1t, gb2p, Btg, Bs1, Bd1, Bs2, Bd2, Bod, Bos);

    // sort e1 by dst
    hipMemsetAsync(cnt, 0, (size_t)(ND + 16) * 4, stream);
    hist_kernel<<<1024, 256, 0, stream>>>(e1_dst, NE1, cnt);
    scanA_kernel<<<98, 256, 0, stream>>>(cnt, ND, chk);
    scanB_kernel<<<1, 256, 0, stream>>>(chk, 98);
    scanC_kernel<<<98, 256, 0, stream>>>(cnt, ND, chk, offs);
    scatter_kernel<<<1024, 256, 0, stream>>>(e1_dst, NE1, offs, perm1);

    // phase 1: drug -> drug (gated)
    hipMemsetAsync(sb, 0, (size_t)ND * NH * 4, stream);
    hipMemsetAsync(aggr, 0, (size_t)ND * DIM * 4, stream);
    proj2m_kernel<<<GRID_M, 256, 0, stream>>>(flag, x_drug, b_src1, b_dst1, Bs1, Bd1, Xs, Xd, ND);
    for (int part = 0; part < nparts; ++part) {
        int c0 = part * cpp, c1 = c0 + cpp;
        if (c1 > NT1) c1 = NT1;
        if (c0 >= c1) break;
        gateall_kernel<<<GRID_G, 256, 0, stream>>>(flag, e1_cat, e1_cont,
                                                   gb2p, B1t, Btg, perm1, gates, c0, c1);
        edge1e_kernel<<<GRID_E1, 256, 0, stream>>>(flag, Xs, Xd, e1_src, e1_dst,
                                                   attn1, perm1, gates, c0, c1, sb, aggr);
    }
    projoutm_kernel<<<GRID_M, 256, 0, stream>>>(flag, aggr, sb, bo_drug, Bod, d_out, 0, ND);

    // sort e2 by dst
    hipMemsetAsync(cnt, 0, (size_t)(NS + 16) * 4, stream);
    hist_kernel<<<1024, 256, 0, stream>>>(e2_dst, NE2, cnt);
    scanA_kernel<<<49, 256, 0, stream>>>(cnt, NS, chk);
    scanB_kernel<<<1, 256, 0, stream>>>(chk, 49);
    scanC_kernel<<<49, 256, 0, stream>>>(cnt, NS, chk, offs);
    scatter_kernel<<<1024, 256, 0, stream>>>(e2_dst, NE2, offs, perm2);

    // phase 2: drug -> disease (no gate)
    hipMemsetAsync(sb, 0, (size_t)NS * NH * 4, stream);
    hipMemsetAsync(aggr, 0, (size_t)NS * DIM * 4, stream);
    proj1m_kernel<<<GRID_M, 256, 0, stream>>>(flag, x_drug, b_src2, Bs2, Xs, ND);
    proj1m_kernel<<<GRID_M, 256, 0, stream>>>(flag, x_dis, b_dst2, Bd2, Xd, NS);
    edge2e_kernel<<<GRID_E2, 256, 0, stream>>>(flag, Xs, Xd, e2_src, e2_dst, attn2, perm2, sb, aggr);
    projoutm_kernel<<<GRID_M, 256, 0, stream>>>(flag, aggr, sb, bo_dis, Bos, d_out, (size_t)ND * DIM, NS);
}

// Round 12
// 689.977 us; speedup vs baseline: 1.1424x; 1.0630x over previous
//
#include <hip/hip_runtime.h>
#include <hip/hip_bf16.h>
#include <math.h>

#define ND 100000
#define NS 50000
#define NE1 500000
#define NE2 250000
#define DIM 128
#define NH 4
#define HDI 32
#define GRID_M 512    // MFMA proj kernels: 2048 waves
#define GRID_G 1024   // gateall: 4096 waves (R11: 2048 regressed — tiles/wave halved, prefetch prologue dominated)
#define GRID_E1 2048  // edge1e: 8192 waves
#define GRID_E2 1024  // edge2e: 4096 waves
#define NT1 (NE1 / 16)  // 31250 sorted 16-edge chunks
#define NT2 (NE2 / 16)  // 15625

typedef __hip_bfloat16 bf16;
typedef unsigned short u16;
typedef unsigned int u32;
typedef short sx8 __attribute__((ext_vector_type(8)));   // 8 bf16 MFMA A/B frag
typedef float fx4 __attribute__((ext_vector_type(4)));   // MFMA C/D frag

__device__ __forceinline__ float ldf(const float* p, size_t i) { return p[i]; }
__device__ __forceinline__ float ldf(const bf16* p, size_t i) { return __bfloat162float(p[i]); }
__device__ __forceinline__ float b2f(bf16 v) { return __bfloat162float(v); }

__device__ __forceinline__ u16 f2bfu(float f) {
    __hip_bfloat16 h = __float2bfloat16(f);
    union { __hip_bfloat16 b; u16 u; } c; c.b = h; return c.u;
}
// unpack a bf16 pair (one dword, little-endian) to two floats
__device__ __forceinline__ float2 bfp(u32 u) {
    float2 r;
    r.x = __uint_as_float(u << 16);
    r.y = __uint_as_float(u & 0xffff0000u);
    return r;
}
__device__ __forceinline__ sx8 pack8(float4 v0, float4 v1) {
    sx8 r;
    r[0] = (short)f2bfu(v0.x); r[1] = (short)f2bfu(v0.y);
    r[2] = (short)f2bfu(v0.z); r[3] = (short)f2bfu(v0.w);
    r[4] = (short)f2bfu(v1.x); r[5] = (short)f2bfu(v1.y);
    r[6] = (short)f2bfu(v1.z); r[7] = (short)f2bfu(v1.w);
    return r;
}
// A-fragment load: 8 consecutive input elems -> bf16x8
__device__ __forceinline__ sx8 lda8(const bf16* p) { return *(const sx8*)p; }
__device__ __forceinline__ sx8 lda8(const float* p) {
    return pack8(*(const float4*)p, *(const float4*)(p + 4));
}
// 4 consecutive values as float4
__device__ __forceinline__ float4 ld4(const float* p) { return *(const float4*)p; }
__device__ __forceinline__ float4 ld4(const bf16* p) {
    float2 a = bfp(*(const u32*)p);
    float2 b = bfp(*(const u32*)(p + 2));
    return make_float4(a.x, a.y, b.x, b.y);
}

// ---------- fast transcendentals (native v_exp/v_rcp; ~1-2 ulp) ----------
__device__ __forceinline__ float gelu_fast(float x) {
    float u2 = x * fmaf(x * x, 0.0713550f, 1.5957691f);
    u2 = fminf(u2, 40.0f);
    float t = __expf(u2);
    return x * t * __builtin_amdgcn_rcpf(t + 1.0f);
}
__device__ __forceinline__ float sigmoid_fast(float x) {
    return __builtin_amdgcn_rcpf(1.0f + __expf(-x));
}
__device__ __forceinline__ float exp_fast(float x) { return __expf(x); }

// ---------- per-wave LDS slab helpers (16 rows x 128 dims f32, XOR-swizzled) ----------
__device__ __forceinline__ void slab_store(float* Gw, const fx4* acc, int er, int lg) {
#pragma unroll
    for (int f = 0; f < 8; ++f)
#pragma unroll
        for (int r = 0; r < 4; ++r) {
            int row = 4 * lg + r;
            int byo = row * 512 + (((16 * f + er) * 4) ^ ((row & 7) << 4));
            *(float*)((char*)Gw + byo) = acc[f][r];
        }
}
__device__ __forceinline__ void slab_flush_bf16(const float* Gw, int lane, bf16* Yrow) {
#pragma unroll
    for (int i = 0; i < 16; ++i) {
        float2 gv = *(const float2*)((const char*)Gw + i * 512 + ((lane * 8) ^ ((i & 7) << 4)));
        u32 pk = ((u32)f2bfu(gv.y) << 16) | (u32)f2bfu(gv.x);
        *(u32*)&Yrow[(size_t)i * DIM + 2 * lane] = pk;
    }
}
__device__ __forceinline__ void sty2(float* p, float2 v) { *(float2*)p = v; }
__device__ __forceinline__ void sty2(bf16* p, float2 v) {
    *(u32*)p = ((u32)f2bfu(v.y) << 16) | (u32)f2bfu(v.x);
}

// ---------- diagnostics ----------
__global__ void fill16_kernel(u16* p, u16 v, size_t n) {
    size_t i = (size_t)blockIdx.x * blockDim.x + threadIdx.x;
    if (i < n) p[i] = v;
}

__global__ __launch_bounds__(64) void detect_kernel(const u16* w, int* flag) {
    int lane = threadIdx.x;
    int mx = 0;
    for (int j = 0; j < 32; ++j) {
        int i = 2 * (lane + 64 * j);
        int e = (w[i] >> 7) & 0xFF;
        mx = mx > e ? mx : e;
    }
    for (int d = 32; d; d >>= 1) { int o = __shfl_xor(mx, d); mx = mx > o ? mx : o; }
    if (lane == 0) flag[0] = (mx >= 0x90) ? 1 : 0;
}

// ---------- counting sort by dst ----------
__global__ __launch_bounds__(256) void hist_kernel(const int* __restrict__ dst, int ne,
                                                   u32* __restrict__ cnt) {
    int stride = gridDim.x * blockDim.x;
    for (int i = blockIdx.x * blockDim.x + threadIdx.x; i < ne; i += stride)
        atomicAdd(&cnt[dst[i]], 1u);
}

__global__ __launch_bounds__(256) void scanA_kernel(const u32* __restrict__ cnt, int nb,
                                                    u32* __restrict__ chk) {
    __shared__ u32 ws[4];
    int b = blockIdx.x, t = threadIdx.x;
    int i0 = b * 1024 + t * 4;
    u32 s = 0;
#pragma unroll
    for (int j = 0; j < 4; ++j) { int i = i0 + j; if (i < nb) s += cnt[i]; }
#pragma unroll
    for (int d = 1; d < 64; d <<= 1) s += __shfl_xor(s, d);
    if ((t & 63) == 0) ws[t >> 6] = s;
    __syncthreads();
    if (t == 0) chk[b] = ws[0] + ws[1] + ws[2] + ws[3];
}

__global__ __launch_bounds__(256) void scanB_kernel(u32* __restrict__ chk, int nc) {
    __shared__ u32 sh[256];
    int t = threadIdx.x;
    u32 v = (t < nc) ? chk[t] : 0u;
    sh[t] = v;
    __syncthreads();
    for (int d = 1; d < 256; d <<= 1) {
        u32 x = (t >= d) ? sh[t - d] : 0u;
        __syncthreads();
        if (t >= d) sh[t] += x;
        __syncthreads();
    }
    if (t < nc) chk[t] = sh[t] - v;
}

__global__ __launch_bounds__(256) void scanC_kernel(const u32* __restrict__ cnt, int nb,
                                                    const u32* __restrict__ chk,
                                                    u32* __restrict__ offs) {
    __shared__ u32 wsum[4];
    int b = blockIdx.x, t = threadIdx.x, lane = t & 63, wv = t >> 6;
    int i0 = b * 1024 + t * 4;
    u32 c0 = (i0 + 0 < nb) ? cnt[i0 + 0] : 0u;
    u32 c1 = (i0 + 1 < nb) ? cnt[i0 + 1] : 0u;
    u32 c2 = (i0 + 2 < nb) ? cnt[i0 + 2] : 0u;
    u32 c3 = (i0 + 3 < nb) ? cnt[i0 + 3] : 0u;
    u32 tot = c0 + c1 + c2 + c3;
    u32 inc = tot;
#pragma unroll
    for (int d = 1; d < 64; d <<= 1) { u32 x = __shfl_up(inc, d); if (lane >= d) inc += x; }
    if (lane == 63) wsum[wv] = inc;
    __syncthreads();
    u32 base = chk[b] + (inc - tot);
    for (int k = 0; k < wv; ++k) base += wsum[k];
    if (i0 + 0 < nb) offs[i0 + 0] = base;
    if (i0 + 1 < nb) offs[i0 + 1] = base + c0;
    if (i0 + 2 < nb) offs[i0 + 2] = base + c0 + c1;
    if (i0 + 3 < nb) offs[i0 + 3] = base + c0 + c1 + c2;
}

__global__ __launch_bounds__(256) void scatter_kernel(const int* __restrict__ dst, int ne,
                                                      u32* __restrict__ offs,
                                                      u32* __restrict__ perm) {
    int stride = gridDim.x * blockDim.x;
    for (int i = blockIdx.x * blockDim.x + threadIdx.x; i < ne; i += stride) {
        u32 p = atomicAdd(&offs[dst[i]], 1u);
        perm[p] = (u32)i;
    }
}

// ---------- prep: bf16 transposed weight tables + gate-MLP constants ----------
template <typename T>
__device__ __forceinline__ void transp(const T* W, u16* Bt, int gtid, int gstride) {
    for (int i = gtid; i < DIM * DIM; i += gstride) {
        int n = i >> 7, k = i & 127;
        Bt[i] = f2bfu(ldf(W, (size_t)k * DIM + n));
    }
}

// B1t[n][k] (n=0..127, k=0..31): k<8 -> gb1[n] + emb[k]@gW1[:32,n] (onehot-cat path);
// 8<=k<12 -> gW1[32+(k-8)][n] (cont path); else 0. GEMM1 becomes one K=32 MFMA.
template <typename T>
__device__ __forceinline__ void prep_body(
    const T* emb, const T* gW1, const T* gb1, const T* gW2,
    const T* Ws1, const T* Wd1, const T* Ws2, const T* Wd2, const T* Wod, const T* Wos,
    u16* B1t, float* gb2f, const T* gb2,
    u16* Btg, u16* Bs1, u16* Bd1, u16* Bs2, u16* Bd2, u16* Bod, u16* Bos)
{
    int gtid = blockIdx.x * blockDim.x + threadIdx.x;
    int gstride = gridDim.x * blockDim.x;
    for (int i = gtid; i < DIM * 32; i += gstride) {
        int n = i >> 5, k = i & 31;
        float v = 0.0f;
        if (k < 8) {
            v = ldf(gb1, n);
            for (int q = 0; q < 32; ++q) v += ldf(emb, k * 32 + q) * ldf(gW1, (size_t)q * DIM + n);
        } else if (k < 12) {
            v = ldf(gW1, (size_t)(32 + (k - 8)) * DIM + n);
        }
        B1t[i] = f2bfu(v);
    }
    for (int i = gtid; i < DIM; i += gstride) gb2f[i] = ldf(gb2, i);
    transp(gW2, Btg, gtid, gstride);
    transp(Ws1, Bs1, gtid, gstride);
    transp(Wd1, Bd1, gtid, gstride);
    transp(Ws2, Bs2, gtid, gstride);
    transp(Wd2, Bd2, gtid, gstride);
    transp(Wod, Bod, gtid, gstride);
    transp(Wos, Bos, gtid, gstride);
}

__global__ __launch_bounds__(256) void prep_kernel(
    const int* __restrict__ flag,
    const void* emb, const void* gW1, const void* gb1, const void* gW2, const void* gb2,
    const void* Ws1, const void* Wd1, const void* Ws2, const void* Wd2,
    const void* Wod, const void* Wos,
    u16* __restrict__ B1t, float* __restrict__ gb2f,
    u16* __restrict__ Btg, u16* __restrict__ Bs1, u16* __restrict__ Bd1,
    u16* __restrict__ Bs2, u16* __restrict__ Bd2, u16* __restrict__ Bod,
    u16* __restrict__ Bos)
{
    if (flag[0])
        prep_body((const float*)emb, (const float*)gW1, (const float*)gb1, (const float*)gW2,
                  (const float*)Ws1, (const float*)Wd1, (const float*)Ws2, (const float*)Wd2,
                  (const float*)Wod, (const float*)Wos,
                  B1t, gb2f, (const float*)gb2, Btg, Bs1, Bd1, Bs2, Bd2, Bod, Bos);
    else
        prep_body((const bf16*)emb, (const bf16*)gW1, (const bf16*)gb1, (const bf16*)gW2,
                  (const bf16*)Ws1, (const bf16*)Wd1, (const bf16*)Ws2, (const bf16*)Wd2,
                  (const bf16*)Wod, (const bf16*)Wos,
                  B1t, gb2f, (const bf16*)gb2, Btg, Bs1, Bd1, Bs2, Bd2, Bod, Bos);
}

// ---------- MFMA node projections: wave per 16-node tile ----------
template <typename T>
__device__ __forceinline__ void proj2m_body(
    float* Gw, const T* X, const T* b1, const T* b2,
    const u16* Bt1, const u16* Bt2, bf16* Y1, bf16* Y2, int N)
{
    int tid = threadIdx.x, lane = tid & 63, er = lane & 15, lg = lane >> 4;
    float c1i[8], c2i[8];
#pragma unroll
    for (int f = 0; f < 8; ++f) {
        c1i[f] = ldf(b1, 16 * f + er);
        c2i[f] = ldf(b2, 16 * f + er);
    }
    const int NW = GRID_M * 4;
    int gwid = blockIdx.x * 4 + (tid >> 6);
    int tiles = N / 16;
    for (int t = gwid; t < tiles; t += NW) {
        const T* xr = X + (size_t)(t * 16 + er) * DIM;
        sx8 a[4];
#pragma unroll
        for (int ks = 0; ks < 4; ++ks) a[ks] = lda8(xr + ks * 32 + lg * 8);
        fx4 acc1[8], acc2[8];
#pragma unroll
        for (int f = 0; f < 8; ++f) {
            acc1[f][0] = c1i[f]; acc1[f][1] = c1i[f]; acc1[f][2] = c1i[f]; acc1[f][3] = c1i[f];
            acc2[f][0] = c2i[f]; acc2[f][1] = c2i[f]; acc2[f][2] = c2i[f]; acc2[f][3] = c2i[f];
        }
#pragma unroll
        for (int ks = 0; ks < 4; ++ks)
#pragma unroll
            for (int f = 0; f < 8; ++f) {
                sx8 bv1 = *(const sx8*)(Bt1 + (size_t)(16 * f + er) * DIM + ks * 32 + lg * 8);
                acc1[f] = __builtin_amdgcn_mfma_f32_16x16x32_bf16(a[ks], bv1, acc1[f], 0, 0, 0);
                sx8 bv2 = *(const sx8*)(Bt2 + (size_t)(16 * f + er) * DIM + ks * 32 + lg * 8);
                acc2[f] = __builtin_amdgcn_mfma_f32_16x16x32_bf16(a[ks], bv2, acc2[f], 0, 0, 0);
            }
        slab_store(Gw, acc1, er, lg);
        slab_flush_bf16(Gw, lane, Y1 + (size_t)t * 16 * DIM);
        slab_store(Gw, acc2, er, lg);
        slab_flush_bf16(Gw, lane, Y2 + (size_t)t * 16 * DIM);
    }
}

__global__ __launch_bounds__(256) void proj2m_kernel(
    const int* __restrict__ flag, const void* X, const void* b1, const void* b2,
    const u16* __restrict__ Bt1, const u16* __restrict__ Bt2,
    bf16* __restrict__ Y1, bf16* __restrict__ Y2, int N)
{
    __shared__ float Gt[4][16 * 128];
    float* Gw = Gt[threadIdx.x >> 6];
    if (flag[0]) proj2m_body(Gw, (const float*)X, (const float*)b1, (const float*)b2, Bt1, Bt2, Y1, Y2, N);
    else         proj2m_body(Gw, (const bf16*)X, (const bf16*)b1, (const bf16*)b2, Bt1, Bt2, Y1, Y2, N);
}

template <typename T>
__device__ __forceinline__ void proj1m_body(
    float* Gw, const T* X, const T* b, const u16* Bt, bf16* Y, int N)
{
    int tid = threadIdx.x, lane = tid & 63, er = lane & 15, lg = lane >> 4;
    float ci[8];
#pragma unroll
    for (int f = 0; f < 8; ++f) ci[f] = ldf(b, 16 * f + er);
    const int NW = GRID_M * 4;
    int gwid = blockIdx.x * 4 + (tid >> 6);
    int tiles = N / 16;
    for (int t = gwid; t < tiles; t += NW) {
        const T* xr = X + (size_t)(t * 16 + er) * DIM;
        sx8 a[4];
#pragma unroll
        for (int ks = 0; ks < 4; ++ks) a[ks] = lda8(xr + ks * 32 + lg * 8);
        fx4 acc[8];
#pragma unroll
        for (int f = 0; f < 8; ++f) {
            acc[f][0] = ci[f]; acc[f][1] = ci[f]; acc[f][2] = ci[f]; acc[f][3] = ci[f];
        }
#pragma unroll
        for (int ks = 0; ks < 4; ++ks)
#pragma unroll
            for (int f = 0; f < 8; ++f) {
                sx8 bv = *(const sx8*)(Bt + (size_t)(16 * f + er) * DIM + ks * 32 + lg * 8);
                acc[f] = __builtin_amdgcn_mfma_f32_16x16x32_bf16(a[ks], bv, acc[f], 0, 0, 0);
            }
        slab_store(Gw, acc, er, lg);
        slab_flush_bf16(Gw, lane, Y + (size_t)t * 16 * DIM);
    }
}

__global__ __launch_bounds__(256) void proj1m_kernel(
    const int* __restrict__ flag, const void* X, const void* b,
    const u16* __restrict__ Bt, bf16* __restrict__ Y, int N)
{
    __shared__ float Gt[4][16 * 128];
    float* Gw = Gt[threadIdx.x >> 6];
    if (flag[0]) proj1m_body(Gw, (const float*)X, (const float*)b, Bt, Y, N);
    else         proj1m_body(Gw, (const bf16*)X, (const bf16*)b, Bt, Y, N);
}

// out[n] = (A[n] / s[n,head]) @ W + b  — division folded into A-fragment load
template <typename T>
__device__ __forceinline__ void projoutm_body(
    float* Gw, const float* A, const float* s, const T* b,
    const u16* Bt, T* out, int N)
{
    int tid = threadIdx.x, lane = tid & 63, er = lane & 15, lg = lane >> 4;
    float ci[8];
#pragma unroll
    for (int f = 0; f < 8; ++f) ci[f] = ldf(b, 16 * f + er);
    const int NW = GRID_M * 4;
    int gwid = blockIdx.x * 4 + (tid >> 6);
    int tiles = N / 16;
    for (int t = gwid; t < tiles; t += NW) {
        const float* ar = A + (size_t)(t * 16 + er) * DIM;
        const float* sr = s + (size_t)(t * 16 + er) * NH;
        sx8 a[4];
#pragma unroll
        for (int ks = 0; ks < 4; ++ks) {
            float inv = 1.0f / (sr[ks] + 1e-16f);   // head == ks for this k-range
            float4 v0 = *(const float4*)(ar + ks * 32 + lg * 8);
            float4 v1 = *(const float4*)(ar + ks * 32 + lg * 8 + 4);
            v0.x *= inv; v0.y *= inv; v0.z *= inv; v0.w *= inv;
            v1.x *= inv; v1.y *= inv; v1.z *= inv; v1.w *= inv;
            a[ks] = pack8(v0, v1);
        }
        fx4 acc[8];
#pragma unroll
        for (int f = 0; f < 8; ++f) {
            acc[f][0] = ci[f]; acc[f][1] = ci[f]; acc[f][2] = ci[f]; acc[f][3] = ci[f];
        }
#pragma unroll
        for (int ks = 0; ks < 4; ++ks)
#pragma unroll
            for (int f = 0; f < 8; ++f) {
                sx8 bv = *(const sx8*)(Bt + (size_t)(16 * f + er) * DIM + ks * 32 + lg * 8);
                acc[f] = __builtin_amdgcn_mfma_f32_16x16x32_bf16(a[ks], bv, acc[f], 0, 0, 0);
            }
        slab_store(Gw, acc, er, lg);
#pragma unroll
        for (int i = 0; i < 16; ++i) {
            float2 gv = *(const float2*)((const char*)Gw + i * 512 + ((lane * 8) ^ ((i & 7) << 4)));
            sty2(out + (size_t)(t * 16 + i) * DIM + 2 * lane, gv);
        }
    }
}

__global__ __launch_bounds__(256) void projoutm_kernel(
    const int* __restrict__ flag, const float* __restrict__ A, const float* __restrict__ s,
    const void* b, const u16* __restrict__ Bt, void* out, size_t off, int N)
{
    __shared__ float Gt[4][16 * 128];
    float* Gw = Gt[threadIdx.x >> 6];
    if (flag[0]) projoutm_body(Gw, A, s, (const float*)b, Bt, (float*)out + off, N);
    else         projoutm_body(Gw, A, s, (const bf16*)b, Bt, (bf16*)out + off, N);
}

// ---------- gate MLP kernel: one-hot MFMA gate + pipelined index prefetch ----------
// Session ledger: R4 no min-waves clamp (spills). R5 no big reg-hoists (occupancy).
// R6 no strided LDS tables (bank conflicts). R7 one-hot MFMA GEMM1. R8 fusion with
// epilogue serializes (283 vs 241). R9 index-chain prefetch (690us BEST). R10 gates
// chunking serializes producer/consumer (+98us of dispatch-gap bubbles). R11 GRID_G
// doubling regresses (tiles/wave halved -> prefetch prologue dominates); depth-2 gather
// pipeline null at 2-4 tiles/wave (prologue ~ half the work). This is the R9 config.
template <typename T>
__device__ __forceinline__ void gateall_body(
    float* Gw, const int* cat, const T* econt,
    const float* gb2f, const u16* B1t, const u16* Btg,
    const u32* perm, u32* gates, int c0, int c1)
{
    int tid = threadIdx.x;
    int lane = tid & 63;
    int er = lane & 15, lg = lane >> 4;

    float cinit[8];
#pragma unroll
    for (int f = 0; f < 8; ++f) cinit[f] = gb2f[16 * f + er];

    const int NW = GRID_G * 4;
    int span = c1 - c0;
    int w = blockIdx.x * 4 + (tid >> 6);
    int tpw = (span + NW - 1) / NW;
    int t0 = c0 + w * tpw, t1 = t0 + tpw;
    if (t1 > c1) t1 = c1;

    const fx4 zf = {0.f, 0.f, 0.f, 0.f};

    // preload tile t0's index/feature chain
    int c = 0;
    float4 fv = make_float4(0.f, 0.f, 0.f, 0.f);
    if (t0 < t1) {
        int e = (int)perm[t0 * 16 + er];
        c = cat[e];
        fv = ld4(econt + (size_t)e * 4);
    }

    for (int t = t0; t < t1; ++t) {
        // ---- prefetch tile t+1's chain (completes under this tile's compute) ----
        int tn = t + 1;
        int e_n = (tn < t1) ? (int)perm[tn * 16 + er] : 0;
        int c_n = cat[e_n];
        float4 fv_n = ld4(econt + (size_t)e_n * 4);

        // ---- A1 fragment in registers: [onehot8(cat), f0..f3, 0...] ----
        sx8 a1;
#pragma unroll
        for (int j = 0; j < 8; ++j) a1[j] = 0;
        if (lg == 0) {
#pragma unroll
            for (int j = 0; j < 8; ++j) a1[j] = (c == j) ? (short)0x3F80 : (short)0;
        } else if (lg == 1) {
            a1[0] = (short)f2bfu(fv.x); a1[1] = (short)f2bfu(fv.y);
            a1[2] = (short)f2bfu(fv.z); a1[3] = (short)f2bfu(fv.w);
        }

        // ---- GEMM1 on MFMA (K=32) ----
        fx4 p1[8];
#pragma unroll
        for (int f = 0; f < 8; ++f) {
            sx8 b1 = *(const sx8*)(B1t + (size_t)(16 * f + er) * 32 + lg * 8);
            p1[f] = __builtin_amdgcn_mfma_f32_16x16x32_bf16(a1, b1, zf, 0, 0, 0);
        }

        // ---- gelu -> swizzled slab (row=edge 4lg+r, col=dim 16f+er) ----
#pragma unroll
        for (int f = 0; f < 8; ++f)
#pragma unroll
            for (int r = 0; r < 4; ++r) {
                int row = 4 * lg + r;
                float hg = gelu_fast(p1[f][r]);
                int byo = row * 512 + (((16 * f + er) * 4) ^ ((row & 7) << 4));
                *(float*)((char*)Gw + byo) = hg;
            }

        // ---- read back h as GEMM2 A-fragments (row=er, dims ks*32+lg*8..+7) ----
        sx8 a2[4];
#pragma unroll
        for (int ks = 0; ks < 4; ++ks) {
            int base = ks * 128 + lg * 32;
            float4 v0 = *(const float4*)((const char*)Gw + er * 512 + ((base)      ^ ((er & 7) << 4)));
            float4 v1 = *(const float4*)((const char*)Gw + er * 512 + ((base + 16) ^ ((er & 7) << 4)));
            a2[ks] = pack8(v0, v1);
        }

        // ---- GEMM2 on MFMA ----
        fx4 acc[8];
#pragma unroll
        for (int f = 0; f < 8; ++f) {
            acc[f][0] = cinit[f]; acc[f][1] = cinit[f];
            acc[f][2] = cinit[f]; acc[f][3] = cinit[f];
        }
#pragma unroll
        for (int ks = 0; ks < 4; ++ks) {
#pragma unroll
            for (int f = 0; f < 8; ++f) {
                sx8 b = *(const sx8*)(Btg + (size_t)(16 * f + er) * DIM + ks * 32 + lg * 8);
                acc[f] = __builtin_amdgcn_mfma_f32_16x16x32_bf16(a2[ks], b, acc[f], 0, 0, 0);
            }
        }

        // ---- sigmoid -> slab ----
#pragma unroll
        for (int f = 0; f < 8; ++f)
#pragma unroll
            for (int r = 0; r < 4; ++r) {
                int row = 4 * lg + r;
                float g = sigmoid_fast(acc[f][r]);
                int byo = row * 512 + (((16 * f + er) * 4) ^ ((row & 7) << 4));
                *(float*)((char*)Gw + byo) = g;
            }

        // ---- pack bf16 pairs; coalesced 256B per edge, sorted-order index ----
#pragma unroll
        for (int i = 0; i < 16; ++i) {
            float2 gv = *(const float2*)((const char*)Gw + i * 512 + ((lane * 8) ^ ((i & 7) << 4)));
            u32 pk = ((u32)f2bfu(gv.y) << 16) | (u32)f2bfu(gv.x);
            gates[((size_t)(t - c0) * 16 + i) * 64 + lane] = pk;
        }

        c = c_n; fv = fv_n;
    }
}

__global__ __launch_bounds__(256) void gateall_kernel(
    const int* __restrict__ flag, const int* __restrict__ cat, const void* econt,
    const float* __restrict__ gb2f, const u16* __restrict__ B1t,
    const u16* __restrict__ Btg,
    const u32* __restrict__ perm, u32* __restrict__ gates, int c0, int c1)
{
    __shared__ float Gt[4][16 * 128];   // 32 KB
    float* Gw = Gt[threadIdx.x >> 6];
    if (flag[0]) gateall_body(Gw, cat, (const float*)econt, gb2f, B1t, Btg, perm, gates, c0, c1);
    else         gateall_body(Gw, cat, (const bf16*)econt, gb2f, B1t, Btg, perm, gates, c0, c1);
}

// ---------- edge1 epilogue: batched prefetch + pipelined index chain ----------
template <typename T>
__device__ __forceinline__ void edge1e_body(
    const bf16* Xs, const bf16* Xd,
    const int* src, const int* dst,
    const T* attn, const u32* perm, const u32* gates, int c0, int c1,
    float* s_out, float* aggr)
{
    int tid = threadIdx.x;
    int lane = tid & 63;
    int d0 = 2 * lane, h = lane >> 4, k0 = d0 & 31;
    float av0 = ldf(attn, h * HDI + k0), av1 = ldf(attn, h * HDI + k0 + 1);
    const float rs = 0.17677669529663688110f;

    const int NW = GRID_E1 * 4;
    int span = c1 - c0;
    int w = blockIdx.x * 4 + (tid >> 6);
    int cpw = (span + NW - 1) / NW;
    int t0 = c0 + w * cpw, t1 = t0 + cpw;
    if (t1 > c1) t1 = c1;

    int cur_di = -1;
    float acc0 = 0.f, acc1 = 0.f, ssum = 0.f;

    // preload tile t0's index chain (perm -> src/dst, 2 round trips)
    u32 sv = 0, dv = 0;
    if (t0 < t1 && lane < 16) {
        u32 pe = perm[t0 * 16 + lane];
        sv = (u32)src[(int)pe];
        dv = (u32)dst[(int)pe];
    }

    for (int t = t0; t < t1; ++t) {
        // prefetch next tile's index chain; completes under this tile's gathers+epilogue
        u32 sv_n = 0, dv_n = 0;
        int tn = t + 1;
        if (tn < t1 && lane < 16) {
            u32 pe_n = perm[tn * 16 + lane];
            sv_n = (u32)src[(int)pe_n];
            dv_n = (u32)dst[(int)pe_n];
        }

        // batched prefetch: 48 independent gathers in flight
        u32 xsp[16], xdp[16], gp[16];
#pragma unroll
        for (int i = 0; i < 16; ++i) {
            int si = (int)__builtin_amdgcn_readlane(sv, i);
            int di = (int)__builtin_amdgcn_readlane(dv, i);
            xsp[i] = *(const u32*)&Xs[(size_t)si * DIM + d0];
            xdp[i] = *(const u32*)&Xd[(size_t)di * DIM + d0];
            gp[i]  = gates[((size_t)(t - c0) * 16 + i) * 64 + lane];
        }
        // register-only compute; 16 independent shuffle/exp chains pipeline
#pragma unroll
        for (int i = 0; i < 16; ++i) {
            int di = (int)__builtin_amdgcn_readlane(dv, i);
            float2 sxy = bfp(xsp[i]);
            float2 dxy = bfp(xdp[i]);
            float2 gxy = bfp(gp[i]);
            if (di != cur_di) {
                if (cur_di >= 0) {
                    float* ap = &aggr[(size_t)cur_di * DIM + d0];
                    atomicAdd(ap, acc0);
                    atomicAdd(ap + 1, acc1);
                    if ((lane & 15) == 0)
                        atomicAdd(&s_out[(size_t)cur_di * NH + h], ssum);
                }
                cur_di = di; acc0 = 0.f; acc1 = 0.f; ssum = 0.f;
            }
            float m0 = (sxy.x + dxy.x) * gxy.x;
            float m1 = (sxy.y + dxy.y) * gxy.y;
            float p = (sxy.x * dxy.x + sxy.y * dxy.y) * rs + m0 * av0 + m1 * av1;
            p += __shfl_xor(p, 8);
            p += __shfl_xor(p, 4);
            p += __shfl_xor(p, 2);
            p += __shfl_xor(p, 1);
            float ev = exp_fast(fminf(p, 80.0f));
            acc0 = fmaf(ev, m0, acc0);
            acc1 = fmaf(ev, m1, acc1);
            ssum += ev;
        }

        sv = sv_n; dv = dv_n;
    }
    if (cur_di >= 0) {
        float* ap = &aggr[(size_t)cur_di * DIM + d0];
        atomicAdd(ap, acc0);
        atomicAdd(ap + 1, acc1);
        if ((lane & 15) == 0)
            atomicAdd(&s_out[(size_t)cur_di * NH + h], ssum);
    }
}

__global__ __launch_bounds__(256) void edge1e_kernel(
    const int* __restrict__ flag,
    const bf16* __restrict__ Xs, const bf16* __restrict__ Xd,
    const int* __restrict__ src, const int* __restrict__ dst,
    const void* attn, const u32* __restrict__ perm, const u32* __restrict__ gates,
    int c0, int c1, float* __restrict__ s_out, float* __restrict__ aggr)
{
    if (flag[0]) edge1e_body(Xs, Xd, src, dst, (const float*)attn, perm, gates, c0, c1, s_out, aggr);
    else         edge1e_body(Xs, Xd, src, dst, (const bf16*)attn, perm, gates, c0, c1, s_out, aggr);
}

// ---------- edge2 epilogue: batched prefetch + pipelined index chain, no gate ----------
template <typename T>
__device__ __forceinline__ void edge2e_body(
    const bf16* Xs, const bf16* Xd,
    const int* src, const int* dst,
    const T* attn, const u32* perm, float* s_out, float* aggr)
{
    int tid = threadIdx.x;
    int lane = tid & 63;
    int d0 = 2 * lane, h = lane >> 4, k0 = d0 & 31;
    float av0 = ldf(attn, h * HDI + k0), av1 = ldf(attn, h * HDI + k0 + 1);
    const float rs = 0.17677669529663688110f;

    const int NW = GRID_E2 * 4;
    int w = blockIdx.x * 4 + (tid >> 6);
    int cpw = (NT2 + NW - 1) / NW;
    int t0 = w * cpw, t1 = t0 + cpw;
    if (t1 > NT2) t1 = NT2;

    int cur_di = -1;
    float acc0 = 0.f, acc1 = 0.f, ssum = 0.f;

    u32 sv = 0, dv = 0;
    if (t0 < t1 && lane < 16) {
        u32 pe = perm[t0 * 16 + lane];
        sv = (u32)src[(int)pe];
        dv = (u32)dst[(int)pe];
    }

    for (int t = t0; t < t1; ++t) {
        u32 sv_n = 0, dv_n = 0;
        int tn = t + 1;
        if (tn < t1 && lane < 16) {
            u32 pe_n = perm[tn * 16 + lane];
            sv_n = (u32)src[(int)pe_n];
            dv_n = (u32)dst[(int)pe_n];
        }

        u32 xsp[16], xdp[16];
#pragma unroll
        for (int i = 0; i < 16; ++i) {
            int si = (int)__builtin_amdgcn_readlane(sv, i);
            int di = (int)__builtin_amdgcn_readlane(dv, i);
            xsp[i] = *(const u32*)&Xs[(size_t)si * DIM + d0];
            xdp[i] = *(const u32*)&Xd[(size_t)di * DIM + d0];
        }
#pragma unroll
        for (int i = 0; i < 16; ++i) {
            int di = (int)__builtin_amdgcn_readlane(dv, i);
            float2 sxy = bfp(xsp[i]);
            float2 dxy = bfp(xdp[i]);
            if (di != cur_di) {
                if (cur_di >= 0) {
                    float* ap = &aggr[(size_t)cur_di * DIM + d0];
                    atomicAdd(ap, acc0);
                    atomicAdd(ap + 1, acc1);
                    if ((lane & 15) == 0)
                        atomicAdd(&s_out[(size_t)cur_di * NH + h], ssum);
                }
                cur_di = di; acc0 = 0.f; acc1 = 0.f; ssum = 0.f;
            }
            float m0 = sxy.x + dxy.x;
            float m1 = sxy.y + dxy.y;
            float p = (sxy.x * dxy.x + sxy.y * dxy.y) * rs + m0 * av0 + m1 * av1;
            p += __shfl_xor(p, 8);
            p += __shfl_xor(p, 4);
            p += __shfl_xor(p, 2);
            p += __shfl_xor(p, 1);
            float ev = exp_fast(fminf(p, 80.0f));
            acc0 = fmaf(ev, m0, acc0);
            acc1 = fmaf(ev, m1, acc1);
            ssum += ev;
        }

        sv = sv_n; dv = dv_n;
    }
    if (cur_di >= 0) {
        float* ap = &aggr[(size_t)cur_di * DIM + d0];
        atomicAdd(ap, acc0);
        atomicAdd(ap + 1, acc1);
        if ((lane & 15) == 0)
            atomicAdd(&s_out[(size_t)cur_di * NH + h], ssum);
    }
}

__global__ __launch_bounds__(256) void edge2e_kernel(
    const int* __restrict__ flag,
    const bf16* __restrict__ Xs, const bf16* __restrict__ Xd,
    const int* __restrict__ src, const int* __restrict__ dst,
    const void* attn, const u32* __restrict__ perm,
    float* __restrict__ s_out, float* __restrict__ aggr)
{
    if (flag[0]) edge2e_body(Xs, Xd, src, dst, (const float*)attn, perm, s_out, aggr);
    else         edge2e_body(Xs, Xd, src, dst, (const bf16*)attn, perm, s_out, aggr);
}

extern "C" void kernel_launch(void* const* d_in, const int* in_sizes, int n_in,
                              void* d_out, int out_size, void* d_ws, size_t ws_size,
                              hipStream_t stream)
{
    const void* x_drug  = d_in[0];
    const void* x_dis   = d_in[1];
    const void* e1_cont = d_in[2];
    const void* W_src1  = d_in[3];
    const void* b_src1  = d_in[4];
    const void* W_dst1  = d_in[5];
    const void* b_dst1  = d_in[6];
    const void* attn1   = d_in[7];
    const void* emb1    = d_in[8];
    const void* gW1     = d_in[9];
    const void* gb1     = d_in[10];
    const void* gW2     = d_in[11];
    const void* gb2     = d_in[12];
    const void* W_src2  = d_in[13];
    const void* b_src2  = d_in[14];
    const void* W_dst2  = d_in[15];
    const void* b_dst2  = d_in[16];
    const void* attn2   = d_in[17];
    const void* Wo_drug = d_in[18];
    const void* bo_drug = d_in[19];
    const void* Wo_dis  = d_in[20];
    const void* bo_dis  = d_in[21];
    const int* e1_src = (const int*)d_in[22];
    const int* e1_dst = (const int*)d_in[23];
    const int* e2_src = (const int*)d_in[24];
    const int* e2_dst = (const int*)d_in[25];
    const int* e1_cat = (const int*)d_in[26];

    bool sizes_ok = (n_in == 27)
        && in_sizes[0] == ND * DIM && in_sizes[1] == NS * DIM
        && in_sizes[2] == NE1 * 4
        && in_sizes[3] == DIM * DIM && in_sizes[4] == DIM
        && in_sizes[5] == DIM * DIM && in_sizes[6] == DIM
        && in_sizes[7] == NH * HDI && in_sizes[8] == 8 * 32
        && in_sizes[9] == 36 * DIM && in_sizes[10] == DIM
        && in_sizes[11] == DIM * DIM && in_sizes[12] == DIM
        && in_sizes[13] == DIM * DIM && in_sizes[17] == NH * HDI
        && in_sizes[18] == DIM * DIM && in_sizes[20] == DIM * DIM
        && in_sizes[22] == NE1 && in_sizes[23] == NE1
        && in_sizes[24] == NE2 && in_sizes[25] == NE2 && in_sizes[26] == NE1;
    if (!sizes_ok) {
        size_t n = (size_t)out_size;
        fill16_kernel<<<(int)((n + 255) / 256), 256, 0, stream>>>((u16*)d_out, 0x429A, n);
        return;
    }

    // fixed workspace layout
    size_t off_B1   = 64;                                     // B1t: [128][32] bf16 = 8KB
    size_t off_g2   = off_B1 + (size_t)DIM * 32 * 2;
    size_t off_Bt   = off_g2 + DIM * 4;                       // Btg (gate)
    size_t off_Bs1  = off_Bt  + (size_t)DIM * DIM * 2;
    size_t off_Bd1  = off_Bs1 + (size_t)DIM * DIM * 2;
    size_t off_Bs2  = off_Bd1 + (size_t)DIM * DIM * 2;
    size_t off_Bd2  = off_Bs2 + (size_t)DIM * DIM * 2;
    size_t off_Bod  = off_Bd2 + (size_t)DIM * DIM * 2;
    size_t off_Bos  = off_Bod + (size_t)DIM * DIM * 2;
    size_t off_Xs   = off_Bos + (size_t)DIM * DIM * 2;
    size_t off_Xd   = off_Xs + (size_t)ND * DIM * 2;
    size_t off_sb   = off_Xd + (size_t)ND * DIM * 2;
    size_t off_aggr = off_sb + (size_t)ND * NH * 4;
    size_t off_cnt  = off_aggr + (size_t)ND * DIM * 4;
    size_t off_offs = off_cnt + (size_t)(ND + 16) * 4;
    size_t off_chk  = off_offs + (size_t)(ND + 16) * 4;
    size_t off_p1   = off_chk + 512;
    size_t off_p2   = off_p1 + (size_t)NE1 * 4;
    size_t off_gate = (off_p2 + (size_t)NE2 * 4 + 255) & ~(size_t)255;
    if (ws_size < off_gate) {
        size_t n = (size_t)out_size;
        fill16_kernel<<<(int)((n + 255) / 256), 256, 0, stream>>>((u16*)d_out, 0x42F6, n);
        return;
    }

    // R10 lesson: nparts=1 (chunking serializes producer/consumer pairs; +98us of gaps).
    // Halve only if the workspace can't hold the full 128MB gates buffer.
    int cpp = NT1;
    while (cpp >= 1024 && off_gate + (size_t)cpp * 16 * 256 > ws_size) cpp >>= 1;
    if (off_gate + (size_t)cpp * 16 * 256 > ws_size) {
        size_t n = (size_t)out_size;
        fill16_kernel<<<(int)((n + 255) / 256), 256, 0, stream>>>((u16*)d_out, 0x42F6, n);
        return;
    }
    int nparts = (NT1 + cpp - 1) / cpp;

    char* w = (char*)d_ws;
    int*   flag = (int*)w;
    u16*   B1t  = (u16*)(w + off_B1);
    float* gb2p = (float*)(w + off_g2);
    u16*   Btg  = (u16*)(w + off_Bt);
    u16*   Bs1  = (u16*)(w + off_Bs1);
    u16*   Bd1  = (u16*)(w + off_Bd1);
    u16*   Bs2  = (u16*)(w + off_Bs2);
    u16*   Bd2  = (u16*)(w + off_Bd2);
    u16*   Bod  = (u16*)(w + off_Bod);
    u16*   Bos  = (u16*)(w + off_Bos);
    bf16*  Xs   = (bf16*)(w + off_Xs);
    bf16*  Xd   = (bf16*)(w + off_Xd);
    float* sb   = (float*)(w + off_sb);
    float* aggr = (float*)(w + off_aggr);
    u32*   cnt  = (u32*)(w + off_cnt);
    u32*   offs = (u32*)(w + off_offs);
    u32*   chk  = (u32*)(w + off_chk);
    u32*   perm1 = (u32*)(w + off_p1);
    u32*   perm2 = (u32*)(w + off_p2);
    u32*   gates = (u32*)(w + off_gate);

    detect_kernel<<<1, 64, 0, stream>>>((const u16*)W_src1, flag);
    prep_kernel<<<64, 256, 0, stream>>>(flag, emb1, gW1, gb1, gW2, gb2,
                                        W_src1, W_dst1, W_src2, W_dst2, Wo_drug, Wo_dis,
                                        B1t, gb2p, Btg, Bs1, Bd1, Bs2, Bd2, Bod, Bos);

    // sort e1 by dst
    hipMemsetAsync(cnt, 0, (size_t)(ND + 16) * 4, stream);
    hist_kernel<<<1024, 256, 0, stream>>>(e1_dst, NE1, cnt);
    scanA_kernel<<<98, 256, 0, stream>>>(cnt, ND, chk);
    scanB_kernel<<<1, 256, 0, stream>>>(chk, 98);
    scanC_kernel<<<98, 256, 0, stream>>>(cnt, ND, chk, offs);
    scatter_kernel<<<1024, 256, 0, stream>>>(e1_dst, NE1, offs, perm1);

    // phase 1: drug -> drug (gated)
    hipMemsetAsync(sb, 0, (size_t)ND * NH * 4, stream);
    hipMemsetAsync(aggr, 0, (size_t)ND * DIM * 4, stream);
    proj2m_kernel<<<GRID_M, 256, 0, stream>>>(flag, x_drug, b_src1, b_dst1, Bs1, Bd1, Xs, Xd, ND);
    for (int part = 0; part < nparts; ++part) {
        int c0 = part * cpp, c1 = c0 + cpp;
        if (c1 > NT1) c1 = NT1;
        if (c0 >= c1) break;
        gateall_kernel<<<GRID_G, 256, 0, stream>>>(flag, e1_cat, e1_cont,
                                                   gb2p, B1t, Btg, perm1, gates, c0, c1);
        edge1e_kernel<<<GRID_E1, 256, 0, stream>>>(flag, Xs, Xd, e1_src, e1_dst,
                                                   attn1, perm1, gates, c0, c1, sb, aggr);
    }
    projoutm_kernel<<<GRID_M, 256, 0, stream>>>(flag, aggr, sb, bo_drug, Bod, d_out, 0, ND);

    // sort e2 by dst
    hipMemsetAsync(cnt, 0, (size_t)(NS + 16) * 4, stream);
    hist_kernel<<<1024, 256, 0, stream>>>(e2_dst, NE2, cnt);
    scanA_kernel<<<49, 256, 0, stream>>>(cnt, NS, chk);
    scanB_kernel<<<1, 256, 0, stream>>>(chk, 49);
    scanC_kernel<<<49, 256, 0, stream>>>(cnt, NS, chk, offs);
    scatter_kernel<<<1024, 256, 0, stream>>>(e2_dst, NE2, offs, perm2);

    // phase 2: drug -> disease (no gate)
    hipMemsetAsync(sb, 0, (size_t)NS * NH * 4, stream);
    hipMemsetAsync(aggr, 0, (size_t)NS * DIM * 4, stream);
    proj1m_kernel<<<GRID_M, 256, 0, stream>>>(flag, x_drug, b_src2, Bs2, Xs, ND);
    proj1m_kernel<<<GRID_M, 256, 0, stream>>>(flag, x_dis, b_dst2, Bd2, Xd, NS);
    edge2e_kernel<<<GRID_E2, 256, 0, stream>>>(flag, Xs, Xd, e2_src, e2_dst, attn2, perm2, sb, aggr);
    projoutm_kernel<<<GRID_M, 256, 0, stream>>>(flag, aggr, sb, bo_dis, Bos, d_out, (size_t)ND * DIM, NS);
}